// Round 2
// baseline (1452.316 us; speedup 1.0000x reference)
//
#include <hip/hip_runtime.h>
#include <hip/hip_bf16.h>

// QMixtralDecoderLayer: B=2 S=1024 D=1024 H=8 KVH=2 HD=128 E=8 TOPK=2 FFN=3584
// int4 group fake-quant (GS=128), RoPE theta=1e6, RMS eps=1e-5.
// Strategy: attention path f32 (router stability), MoE in bf16 MFMA.

typedef __attribute__((ext_vector_type(4))) float f32x4;
typedef __attribute__((ext_vector_type(8))) short short8;
typedef __hip_bfloat16 bf16;

#define DEV static __device__ __forceinline__

DEV float wsum(float v){
  #pragma unroll
  for (int o=32;o>0;o>>=1) v += __shfl_xor(v,o,64);
  return v;
}
DEV float wmaxr(float v){
  #pragma unroll
  for (int o=32;o>0;o>>=1) v = fmaxf(v,__shfl_xor(v,o,64));
  return v;
}
DEV float wminr(float v){
  #pragma unroll
  for (int o=32;o>0;o>>=1) v = fminf(v,__shfl_xor(v,o,64));
  return v;
}
// matches: (clip(round(x/s)+b,0,15)-b)*s with round-half-even
DEV float fakeq(float x, float s, float b){
  return (fminf(fmaxf(rintf(x/s)+b,0.f),15.f)-b)*s;
}

// ---------------- workspace layout (bytes) ----------------
constexpr size_t OFF_WQKV = 0;                         // 1536*1024 f32 (dequant wq|wk|wv)
constexpr size_t OFF_WO   = OFF_WQKV + 6291456;        // 1024*1024 f32
constexpr size_t OFF_W1Q  = OFF_WO   + 4194304;        // 8*3584*1024 bf16
constexpr size_t OFF_W3Q  = OFF_W1Q  + 58720256;
constexpr size_t OFF_W2Q  = OFF_W3Q  + 58720256;
constexpr size_t OFF_QKV  = OFF_W2Q  + 58720256;       // 2048*1536 f32
constexpr size_t OFF_SC   = OFF_QKV  + 12582912;       // 16*1024*1024 f32; later UP 4*2048*3584 bf16
constexpr size_t OFF_O2   = OFF_SC   + 67108864;       // 2048*1024 f32
constexpr size_t OFF_H    = OFF_O2   + 8388608;        // 2048*1024 f32
constexpr size_t OFF_XN   = OFF_H    + 8388608;        // xn then hn (f32)
constexpr size_t OFF_HNB  = OFF_XN   + 8388608;        // hn bf16
constexpr size_t OFF_COS  = OFF_HNB  + 4194304;        // 1024*64 f32
constexpr size_t OFF_SIN  = OFF_COS  + 262144;
constexpr size_t OFF_CNT  = OFF_SIN  + 262144;         // 8 ints (+pad)
constexpr size_t OFF_TOK  = OFF_CNT  + 256;            // 8*2048 int
constexpr size_t OFF_WTS  = OFF_TOK  + 65536;          // 8*2048 f32
constexpr size_t OFF_MA   = OFF_WTS  + 65536;          // 2048*1024 f32
constexpr size_t OFF_MB   = OFF_MA   + 8388608;
constexpr size_t WS_NEED  = OFF_MB   + 8388608;        // ~299 MB

__global__ void k_sentinel(float* out){ out[0] = 12345.0f; }
__global__ void k_zero(int* cnt){ if (threadIdx.x < 8) cnt[threadIdx.x] = 0; }

// ---------------- RMSNorm (f32 in, f32 out + optional bf16 out) ----------------
__global__ __launch_bounds__(256) void k_rms(const float* __restrict__ x,
                                             const float* __restrict__ g,
                                             float* __restrict__ out,
                                             bf16* __restrict__ outb)
{
  int row = blockIdx.x, tid = threadIdx.x;
  const float4* x4 = (const float4*)(x + (size_t)row*1024);
  float4 v = x4[tid];
  float ss = v.x*v.x + v.y*v.y + v.z*v.z + v.w*v.w;
  int lane = tid & 63, wv = tid >> 6;
  ss = wsum(ss);
  __shared__ float red[4];
  if (lane == 0) red[wv] = ss;
  __syncthreads();
  float tot = red[0]+red[1]+red[2]+red[3];
  float r = 1.0f / sqrtf(tot * (1.0f/1024.0f) + 1e-5f);
  float4 gg = ((const float4*)g)[tid];
  float4 o;
  o.x = v.x*r*gg.x; o.y = v.y*r*gg.y; o.z = v.z*r*gg.z; o.w = v.w*r*gg.w;
  ((float4*)(out + (size_t)row*1024))[tid] = o;
  if (outb) {
    bf16* ob = outb + (size_t)row*1024 + tid*4;
    ob[0]=__float2bfloat16(o.x); ob[1]=__float2bfloat16(o.y);
    ob[2]=__float2bfloat16(o.z); ob[3]=__float2bfloat16(o.w);
  }
}

// ---------------- weight dequant: attention (f32 out) ----------------
// groups: wq 8192, wk 2048, wv 2048, wo 8192  (1 wave per 128-elem group)
__global__ __launch_bounds__(256) void k_dequant_attn(
    const float* __restrict__ wq, const float* __restrict__ wk,
    const float* __restrict__ wv, const float* __restrict__ wo,
    float* __restrict__ wqkv, float* __restrict__ wod)
{
  int g = blockIdx.x*4 + (threadIdx.x>>6);
  int lane = threadIdx.x & 63;
  const float* src; float* dst;
  if (g < 8192)       { size_t o=(size_t)g*128;          src = wq + o; dst = wqkv + o; }
  else if (g < 10240) { size_t o=(size_t)(g-8192)*128;   src = wk + o; dst = wqkv + (size_t)1024*1024 + o; }
  else if (g < 12288) { size_t o=(size_t)(g-10240)*128;  src = wv + o; dst = wqkv + (size_t)1280*1024 + o; }
  else                { size_t o=(size_t)(g-12288)*128;  src = wo + o; dst = wod + o; }
  float x0 = src[lane], x1 = src[lane+64];
  float mn = wminr(fminf(x0,x1));
  float mx = wmaxr(fmaxf(x0,x1));
  float s = fmaxf(mx-mn, 1e-5f) / 15.0f;
  float b = fminf(fmaxf(rintf(-mn/s),0.f),15.f);
  dst[lane]    = fakeq(x0,s,b);
  dst[lane+64] = fakeq(x1,s,b);
}

// ---------------- weight dequant: MoE (bf16 out) ----------------
__global__ __launch_bounds__(256) void k_dequant_moe(
    const float* __restrict__ w1, const float* __restrict__ w3,
    const float* __restrict__ w2,
    bf16* __restrict__ o1, bf16* __restrict__ o3, bf16* __restrict__ o2q)
{
  int g = blockIdx.x*4 + (threadIdx.x>>6);  // 0..688127
  int lane = threadIdx.x & 63;
  const int NG = 229376;                    // 8*3584*1024/128
  int t = g / NG, gl = g - t*NG;
  const float* src; bf16* dst;
  if (t == 0)      { src = w1; dst = o1; }
  else if (t == 1) { src = w3; dst = o3; }
  else             { src = w2; dst = o2q; }
  src += (size_t)gl*128; dst += (size_t)gl*128;
  float x0 = src[lane], x1 = src[lane+64];
  float mn = wminr(fminf(x0,x1));
  float mx = wmaxr(fmaxf(x0,x1));
  float s = fmaxf(mx-mn, 1e-5f) / 15.0f;
  float b = fminf(fmaxf(rintf(-mn/s),0.f),15.f);
  dst[lane]    = __float2bfloat16(fakeq(x0,s,b));
  dst[lane+64] = __float2bfloat16(fakeq(x1,s,b));
}

// ---------------- RoPE tables ----------------
__global__ __launch_bounds__(256) void k_rope_tab(float* ct, float* st)
{
  int s = blockIdx.x*4 + (threadIdx.x>>6);
  int l = threadIdx.x & 63;
  float inv = 1.0f / powf(1.0e6f, (float)l * (1.0f/64.0f));
  float f = (float)s * inv;
  ct[s*64 + l] = cosf(f);
  st[s*64 + l] = sinf(f);
}

// ---------------- f32 GEMM core: C[M,N] = A[M,K] * B[N,K]^T (tile 128x64) ----------------
DEV void gemm_bt_128x64(const float* __restrict__ A, int lda,
                        const float* __restrict__ Bm, int ldb,
                        float* __restrict__ C, int ldc,
                        const float* __restrict__ resid,
                        int K, float scale, int m0, int n0)
{
  __shared__ float As[16*136];
  __shared__ float Bs[16*72];
  int tid = threadIdx.x;
  int ar = tid >> 1, ak = (tid & 1) * 8;
  int br = tid >> 2, bk = (tid & 3) * 4;
  const float* ap = A + (size_t)(m0 + ar)*lda + ak;
  const float* bp = Bm + (size_t)(n0 + br)*ldb + bk;
  int ty = tid >> 4, tx = tid & 15;
  int r0 = ty*8, c0 = tx*4;
  float acc[8][4];
  #pragma unroll
  for (int i=0;i<8;i++){
    #pragma unroll
    for (int j=0;j<4;j++) acc[i][j]=0.f;
  }
  for (int k0 = 0; k0 < K; k0 += 16) {
    float4 a0 = *(const float4*)(ap + k0);
    float4 a1 = *(const float4*)(ap + k0 + 4);
    float4 b0 = *(const float4*)(bp + k0);
    __syncthreads();
    As[(ak+0)*136+ar]=a0.x; As[(ak+1)*136+ar]=a0.y; As[(ak+2)*136+ar]=a0.z; As[(ak+3)*136+ar]=a0.w;
    As[(ak+4)*136+ar]=a1.x; As[(ak+5)*136+ar]=a1.y; As[(ak+6)*136+ar]=a1.z; As[(ak+7)*136+ar]=a1.w;
    Bs[(bk+0)*72+br]=b0.x;  Bs[(bk+1)*72+br]=b0.y;  Bs[(bk+2)*72+br]=b0.z;  Bs[(bk+3)*72+br]=b0.w;
    __syncthreads();
    #pragma unroll
    for (int kk = 0; kk < 16; kk++) {
      float4 xa = *(const float4*)&As[kk*136 + r0];
      float4 xb = *(const float4*)&As[kk*136 + r0 + 4];
      float4 yb = *(const float4*)&Bs[kk*72 + c0];
      float xs[8] = {xa.x,xa.y,xa.z,xa.w,xb.x,xb.y,xb.z,xb.w};
      float ys[4] = {yb.x,yb.y,yb.z,yb.w};
      #pragma unroll
      for (int i=0;i<8;i++){
        #pragma unroll
        for (int j=0;j<4;j++) acc[i][j] += xs[i]*ys[j];
      }
    }
  }
  #pragma unroll
  for (int i=0;i<8;i++){
    size_t ro = (size_t)(m0 + r0 + i)*ldc + n0 + c0;
    #pragma unroll
    for (int j=0;j<4;j++){
      float v = acc[i][j]*scale;
      if (resid) v += resid[ro + j];
      C[ro + j] = v;
    }
  }
}

__global__ __launch_bounds__(256) void k_qkv_gemm(const float* xn, const float* wqkv, float* qkv){
  gemm_bt_128x64(xn, 1024, wqkv, 1024, qkv, 1536, nullptr, 1024, 1.0f,
                 blockIdx.y*128, blockIdx.x*64);
}
__global__ __launch_bounds__(256) void k_wo(const float* o2, const float* wod,
                                            const float* hidden, float* h){
  gemm_bt_128x64(o2, 1024, wod, 1024, h, 1024, hidden, 1024, 1.0f,
                 blockIdx.y*128, blockIdx.x*64);
}
__global__ __launch_bounds__(256) void k_scores(const float* qkv, float* sc){
  int z = blockIdx.z, b = z >> 3, h = z & 7;
  int m0 = blockIdx.y*128, n0 = blockIdx.x*64;
  if (n0 > m0 + 127) return;   // fully-masked causal tile
  const float* A  = qkv + (size_t)b*1024*1536 + h*128;
  const float* Bp = qkv + (size_t)b*1024*1536 + 1024 + (h>>2)*128;
  float* C = sc + (size_t)z*1024*1024;
  gemm_bt_128x64(A, 1536, Bp, 1536, C, 1024, nullptr, 128, 0.08838834764831845f, m0, n0);
}

// ---------------- f32 GEMM core: C = A[M,K]*B[K,N] (tile 64x64), for attn@V ----------------
DEV void gemm_nn_64x64(const float* __restrict__ A, int lda,
                       const float* __restrict__ Bm, int ldb,
                       float* __restrict__ C, int ldc,
                       int kmax, int m0, int n0)
{
  __shared__ float As[16*68];
  __shared__ float Bs[16*68];
  int tid = threadIdx.x;
  int ar = tid >> 2, ak = (tid & 3)*4;
  int bk = tid >> 4, bc = (tid & 15)*4;
  const float* ap = A + (size_t)(m0 + ar)*lda + ak;
  const float* bp = Bm + (size_t)bk*ldb + n0 + bc;
  int ty = tid >> 4, tx = tid & 15;
  int r0 = ty*4, c0 = tx*4;
  float acc[4][4];
  #pragma unroll
  for (int i=0;i<4;i++){
    #pragma unroll
    for (int j=0;j<4;j++) acc[i][j]=0.f;
  }
  for (int k0 = 0; k0 < kmax; k0 += 16) {
    float4 a = *(const float4*)(ap + k0);
    float4 b = *(const float4*)(bp + (size_t)k0*ldb);
    __syncthreads();
    As[(ak+0)*68+ar]=a.x; As[(ak+1)*68+ar]=a.y; As[(ak+2)*68+ar]=a.z; As[(ak+3)*68+ar]=a.w;
    *(float4*)&Bs[bk*68 + bc] = b;
    __syncthreads();
    #pragma unroll
    for (int kk = 0; kk < 16; kk++) {
      float4 xa = *(const float4*)&As[kk*68 + r0];
      float4 yb = *(const float4*)&Bs[kk*68 + c0];
      float xs[4] = {xa.x,xa.y,xa.z,xa.w};
      float ys[4] = {yb.x,yb.y,yb.z,yb.w};
      #pragma unroll
      for (int i=0;i<4;i++){
        #pragma unroll
        for (int j=0;j<4;j++) acc[i][j] += xs[i]*ys[j];
      }
    }
  }
  #pragma unroll
  for (int i=0;i<4;i++){
    size_t ro = (size_t)(m0 + r0 + i)*ldc + n0 + c0;
    #pragma unroll
    for (int j=0;j<4;j++) C[ro + j] = acc[i][j];
  }
}

__global__ __launch_bounds__(256) void k_pv(const float* sc, const float* qkv, float* o2){
  int z = blockIdx.z, b = z >> 3, h = z & 7;
  int m0 = blockIdx.y*64, n0 = blockIdx.x*64;
  const float* A  = sc + (size_t)z*1024*1024;
  const float* Bp = qkv + (size_t)b*1024*1536 + 1280 + (h>>2)*128;
  float* C = o2 + (size_t)b*1024*1024 + h*128;
  gemm_nn_64x64(A, 1024, Bp, 1536, C, 1024, m0 + 64 /*causal kmax*/, m0, n0);
}

// ---------------- RoPE q (in-place in qkv) ----------------
__global__ __launch_bounds__(256) void k_rope_q(float* qkv, const float* ct, const float* st){
  int wid = blockIdx.x*4 + (threadIdx.x>>6);   // 0..16383
  int lane = threadIdx.x & 63;
  int t = wid >> 3, h = wid & 7;
  int s = t & 1023;
  float* base = qkv + (size_t)t*1536 + h*128;
  float x0 = base[lane], x1 = base[lane+64];
  float c = ct[s*64+lane], sn = st[s*64+lane];
  base[lane]    = x0*c - x1*sn;
  base[lane+64] = x1*c + x0*sn;
}

// ---------------- k: fake-quant then RoPE; v: fake-quant (in-place) ----------------
__global__ __launch_bounds__(256) void k_kv(float* qkv, const float* ct, const float* st){
  int wid = blockIdx.x*4 + (threadIdx.x>>6);   // 0..4095
  int lane = threadIdx.x & 63;
  int t = wid >> 1, kvh = wid & 1;
  int s = t & 1023;
  float* kb = qkv + (size_t)t*1536 + 1024 + kvh*128;
  float* vb = qkv + (size_t)t*1536 + 1280 + kvh*128;
  float k0v = kb[lane], k1v = kb[lane+64];
  float v0v = vb[lane], v1v = vb[lane+64];
  float mn = wminr(fminf(k0v,k1v));
  float mx = wmaxr(fmaxf(k0v,k1v));
  float sc = fmaxf(mx-mn,1e-5f)/15.0f;
  float bs = fminf(fmaxf(rintf(-mn/sc),0.f),15.f);
  float kq0 = fakeq(k0v,sc,bs), kq1 = fakeq(k1v,sc,bs);
  float c = ct[s*64+lane], sn = st[s*64+lane];
  kb[lane]    = kq0*c - kq1*sn;
  kb[lane+64] = kq1*c + kq0*sn;
  mn = wminr(fminf(v0v,v1v));
  mx = wmaxr(fmaxf(v0v,v1v));
  sc = fmaxf(mx-mn,1e-5f)/15.0f;
  bs = fminf(fmaxf(rintf(-mn/sc),0.f),15.f);
  vb[lane]    = fakeq(v0v,sc,bs);
  vb[lane+64] = fakeq(v1v,sc,bs);
}

// ---------------- causal softmax over scores rows (in-place) ----------------
__global__ __launch_bounds__(256) void k_softmax(float* sc){
  int row = blockIdx.x;                 // 16384 = 16*1024
  int i = row & 1023;                   // query position
  float* p = sc + (size_t)row*1024;
  int tid = threadIdx.x, lane = tid & 63, wv = tid >> 6;
  float v[4];
  float m = -3.0e38f;
  #pragma unroll
  for (int k2=0;k2<4;k2++){
    int j = tid + k2*256;
    v[k2] = p[j];
    if (j <= i) m = fmaxf(m, v[k2]);
  }
  __shared__ float red[4];
  m = wmaxr(m);
  if (lane==0) red[wv] = m;
  __syncthreads();
  m = fmaxf(fmaxf(red[0],red[1]), fmaxf(red[2],red[3]));
  float ls = 0.f;
  #pragma unroll
  for (int k2=0;k2<4;k2++){
    int j = tid + k2*256;
    float e = (j <= i) ? __expf(v[k2]-m) : 0.0f;
    v[k2] = e; ls += e;
  }
  __syncthreads();
  ls = wsum(ls);
  if (lane==0) red[wv] = ls;
  __syncthreads();
  float inv = 1.0f / (red[0]+red[1]+red[2]+red[3]);
  #pragma unroll
  for (int k2=0;k2<4;k2++){
    int j = tid + k2*256;
    p[j] = v[k2]*inv;
  }
}

// ---------------- router: logits, softmax, stable top-2, scatter ----------------
__global__ __launch_bounds__(256) void k_router(const float* __restrict__ hn,
                                                const float* __restrict__ wg,
                                                int* cnt, int* toksl, float* wts){
  int t = blockIdx.x*4 + (threadIdx.x>>6);
  int lane = threadIdx.x & 63;
  const float* x = hn + (size_t)t*1024;
  float p[8];
  #pragma unroll
  for (int e=0;e<8;e++) p[e]=0.f;
  for (int i=0;i<16;i++){
    float xv = x[lane + i*64];
    #pragma unroll
    for (int e=0;e<8;e++) p[e] += xv * wg[e*1024 + lane + i*64];
  }
  #pragma unroll
  for (int e=0;e<8;e++) p[e] = wsum(p[e]);
  if (lane==0){
    float m = p[0];
    for (int e=1;e<8;e++) m = fmaxf(m,p[e]);
    float ex[8], sum=0.f;
    for (int e=0;e<8;e++){ ex[e]=__expf(p[e]-m); sum+=ex[e]; }
    float pr[8];
    for (int e=0;e<8;e++) pr[e]=ex[e]/sum;
    int i1 = 0;
    for (int e=1;e<8;e++) if (pr[e] > pr[i1]) i1 = e;   // ties -> lowest idx (stable)
    int i2 = -1;
    for (int e=0;e<8;e++){ if (e==i1) continue; if (i2<0 || pr[e] > pr[i2]) i2 = e; }
    float ssum = pr[i1]+pr[i2];
    float wa = pr[i1]/ssum, wb = pr[i2]/ssum;
    int pos = atomicAdd(cnt+i1,1);
    toksl[i1*2048+pos] = t;          wts[i1*2048+pos] = wa;
    pos = atomicAdd(cnt+i2,1);
    toksl[i2*2048+pos] = t | 65536;  wts[i2*2048+pos] = wb;
  }
}

// ---------------- MoE GEMM1: up = silu(hn@w1^T) * (hn@w3^T), gathered tokens ----------------
// block tile 64(tokens) x 128(ffn), K=1024 step 32, 16x16x32 bf16 MFMA, dual B
__global__ __launch_bounds__(256) void k_moe_gemm1(
    const bf16* __restrict__ hnb, const bf16* __restrict__ w1q, const bf16* __restrict__ w3q,
    const int* __restrict__ cnt, const int* __restrict__ toksl,
    bf16* __restrict__ up, int ebase)
{
  int el = blockIdx.z, e = ebase + el;
  int c = cnt[e];
  int m0 = blockIdx.x * 64;
  if (m0 >= c) return;
  int n0 = blockIdx.y * 128;
  __shared__ bf16 As[64*40];
  __shared__ bf16 B1s[128*40];
  __shared__ bf16 B3s[128*40];
  int tid = threadIdx.x, lane = tid & 63, wv = tid >> 6;
  int arow = tid >> 2, acol = (tid & 3) * 8;
  int slot = m0 + arow;
  int tok = (slot < c) ? (toksl[e*2048 + slot] & 0xFFFF) : 0;
  const bf16* ap  = hnb + (size_t)tok*1024 + acol;
  const bf16* b1p = w1q + ((size_t)e*3584 + n0 + arow)*1024 + acol;
  const bf16* b3p = w3q + ((size_t)e*3584 + n0 + arow)*1024 + acol;
  f32x4 zero = {0.f,0.f,0.f,0.f};
  f32x4 acc1[4][2], acc3[4][2];
  #pragma unroll
  for (int i=0;i<4;i++){ acc1[i][0]=zero; acc1[i][1]=zero; acc3[i][0]=zero; acc3[i][1]=zero; }
  int fr = lane & 15, fq = lane >> 4;
  for (int k0 = 0; k0 < 1024; k0 += 32) {
    short8 av  = *(const short8*)(ap + k0);
    short8 b1a = *(const short8*)(b1p + k0);
    short8 b1b = *(const short8*)(b1p + (size_t)64*1024 + k0);
    short8 b3a = *(const short8*)(b3p + k0);
    short8 b3b = *(const short8*)(b3p + (size_t)64*1024 + k0);
    __syncthreads();
    *(short8*)&As[arow*40 + acol] = av;
    *(short8*)&B1s[arow*40 + acol] = b1a;
    *(short8*)&B1s[(arow+64)*40 + acol] = b1b;
    *(short8*)&B3s[arow*40 + acol] = b3a;
    *(short8*)&B3s[(arow+64)*40 + acol] = b3b;
    __syncthreads();
    short8 aF[4];
    #pragma unroll
    for (int mt=0; mt<4; mt++) aF[mt] = *(const short8*)&As[(mt*16+fr)*40 + fq*8];
    #pragma unroll
    for (int nt=0; nt<2; nt++){
      short8 b1F = *(const short8*)&B1s[(wv*32 + nt*16 + fr)*40 + fq*8];
      short8 b3F = *(const short8*)&B3s[(wv*32 + nt*16 + fr)*40 + fq*8];
      #pragma unroll
      for (int mt=0; mt<4; mt++){
        acc1[mt][nt] = __builtin_amdgcn_mfma_f32_16x16x32_bf16(aF[mt], b1F, acc1[mt][nt], 0,0,0);
        acc3[mt][nt] = __builtin_amdgcn_mfma_f32_16x16x32_bf16(aF[mt], b3F, acc3[mt][nt], 0,0,0);
      }
    }
  }
  bf16* upb = up + (size_t)el*2048*3584;
  #pragma unroll
  for (int mt=0; mt<4; mt++){
    #pragma unroll
    for (int nt=0; nt<2; nt++){
      #pragma unroll
      for (int r=0; r<4; r++){
        int srow = m0 + mt*16 + fq*4 + r;          // C layout: row=(lane>>4)*4+reg
        int fcol = n0 + wv*32 + nt*16 + fr;        //           col=lane&15
        float x1 = acc1[mt][nt][r], x3 = acc3[mt][nt][r];
        float u = (x1 / (1.0f + __expf(-x1))) * x3;
        upb[(size_t)srow*3584 + fcol] = __float2bfloat16(u);
      }
    }
  }
}

// ---------------- MoE GEMM2: moe = wt * (up @ w2^T), scatter to moeA/moeB ----------------
__global__ __launch_bounds__(256) void k_moe_gemm2(
    const bf16* __restrict__ up, const bf16* __restrict__ w2q,
    const int* __restrict__ cnt, const int* __restrict__ toksl,
    const float* __restrict__ wts,
    float* __restrict__ moeA, float* __restrict__ moeB, int ebase)
{
  int el = blockIdx.z, e = ebase + el;
  int c = cnt[e];
  int m0 = blockIdx.x * 64;
  if (m0 >= c) return;
  int n0 = blockIdx.y * 128;
  __shared__ bf16 As[64*40];
  __shared__ bf16 Bs[128*40];
  int tid = threadIdx.x, lane = tid & 63, wv = tid >> 6;
  int arow = tid >> 2, acol = (tid & 3) * 8;
  const bf16* ap = up + (size_t)el*2048*3584 + (size_t)(m0 + arow)*3584 + acol;
  const bf16* bp = w2q + ((size_t)e*1024 + n0 + arow)*3584 + acol;
  f32x4 zero = {0.f,0.f,0.f,0.f};
  f32x4 acc[4][2];
  #pragma unroll
  for (int i=0;i<4;i++){ acc[i][0]=zero; acc[i][1]=zero; }
  int fr = lane & 15, fq = lane >> 4;
  for (int k0 = 0; k0 < 3584; k0 += 32) {
    short8 av = *(const short8*)(ap + k0);
    short8 ba = *(const short8*)(bp + k0);
    short8 bb = *(const short8*)(bp + (size_t)64*3584 + k0);
    __syncthreads();
    *(short8*)&As[arow*40 + acol] = av;
    *(short8*)&Bs[arow*40 + acol] = ba;
    *(short8*)&Bs[(arow+64)*40 + acol] = bb;
    __syncthreads();
    short8 aF[4];
    #pragma unroll
    for (int mt=0; mt<4; mt++) aF[mt] = *(const short8*)&As[(mt*16+fr)*40 + fq*8];
    #pragma unroll
    for (int nt=0; nt<2; nt++){
      short8 bF = *(const short8*)&Bs[(wv*32 + nt*16 + fr)*40 + fq*8];
      #pragma unroll
      for (int mt=0; mt<4; mt++)
        acc[mt][nt] = __builtin_amdgcn_mfma_f32_16x16x32_bf16(aF[mt], bF, acc[mt][nt], 0,0,0);
    }
  }
  #pragma unroll
  for (int mt=0; mt<4; mt++){
    #pragma unroll
    for (int nt=0; nt<2; nt++){
      #pragma unroll
      for (int r=0; r<4; r++){
        int srow = m0 + mt*16 + fq*4 + r;
        if (srow < c){
          int ts = toksl[e*2048 + srow];
          int tok = ts & 0xFFFF, fl = ts >> 16;
          float wt = wts[e*2048 + srow];
          int d = n0 + wv*32 + nt*16 + fr;
          float* dst = (fl ? moeB : moeA) + (size_t)tok*1024 + d;
          *dst = acc[mt][nt][r] * wt;
        }
      }
    }
  }
}

// ---------------- final: out = h + moeA + moeB ----------------
__global__ __launch_bounds__(256) void k_final(const float* h, const float* ma,
                                               const float* mb, float* out){
  size_t i = (size_t)blockIdx.x*256 + threadIdx.x;
  float4 a = ((const float4*)h)[i];
  float4 b = ((const float4*)ma)[i];
  float4 c = ((const float4*)mb)[i];
  float4 o;
  o.x = a.x+b.x+c.x; o.y = a.y+b.y+c.y; o.z = a.z+b.z+c.z; o.w = a.w+b.w+c.w;
  ((float4*)out)[i] = o;
}

extern "C" void kernel_launch(void* const* d_in, const int* in_sizes, int n_in,
                              void* d_out, int out_size, void* d_ws, size_t ws_size,
                              hipStream_t stream)
{
  (void)in_sizes; (void)n_in; (void)out_size;
  float* out = (float*)d_out;
  if (ws_size < WS_NEED) { k_sentinel<<<1,1,0,stream>>>(out); return; } // ws too small -> absmax ~12345 marker

  const float* hidden = (const float*)d_in[0];
  const float* w_q  = (const float*)d_in[1];
  const float* w_k  = (const float*)d_in[2];
  const float* w_v  = (const float*)d_in[3];
  const float* w_o  = (const float*)d_in[4];
  const float* g1   = (const float*)d_in[5];
  const float* g2   = (const float*)d_in[6];
  const float* wg   = (const float*)d_in[7];
  const float* w1   = (const float*)d_in[8];
  const float* w3   = (const float*)d_in[9];
  const float* w2   = (const float*)d_in[10];
  char* ws = (char*)d_ws;
  float* WQKV = (float*)(ws + OFF_WQKV);
  float* WOD  = (float*)(ws + OFF_WO);
  bf16*  W1Q  = (bf16*)(ws + OFF_W1Q);
  bf16*  W3Q  = (bf16*)(ws + OFF_W3Q);
  bf16*  W2Q  = (bf16*)(ws + OFF_W2Q);
  float* QKV  = (float*)(ws + OFF_QKV);
  float* SC   = (float*)(ws + OFF_SC);
  bf16*  UP   = (bf16*)(ws + OFF_SC);    // aliases SC (scores dead before MoE)
  float* O2b  = (float*)(ws + OFF_O2);
  float* Hb   = (float*)(ws + OFF_H);
  float* XN   = (float*)(ws + OFF_XN);   // xn, later hn (f32)
  bf16*  HNB  = (bf16*)(ws + OFF_HNB);
  float* CT   = (float*)(ws + OFF_COS);
  float* ST   = (float*)(ws + OFF_SIN);
  int*   CNT  = (int*)(ws + OFF_CNT);
  int*   TOK  = (int*)(ws + OFF_TOK);
  float* WTS  = (float*)(ws + OFF_WTS);
  float* MA   = (float*)(ws + OFF_MA);
  float* MB   = (float*)(ws + OFF_MB);

  k_zero<<<1,64,0,stream>>>(CNT);
  k_rms<<<2048,256,0,stream>>>(hidden, g1, XN, (bf16*)nullptr);
  k_dequant_attn<<<5120,256,0,stream>>>(w_q, w_k, w_v, w_o, WQKV, WOD);
  k_dequant_moe<<<172032,256,0,stream>>>(w1, w3, w2, W1Q, W3Q, W2Q);
  k_rope_tab<<<256,256,0,stream>>>(CT, ST);
  k_qkv_gemm<<<dim3(24,16),256,0,stream>>>(XN, WQKV, QKV);
  k_rope_q<<<4096,256,0,stream>>>(QKV, CT, ST);
  k_kv<<<1024,256,0,stream>>>(QKV, CT, ST);
  k_scores<<<dim3(16,8,16),256,0,stream>>>(QKV, SC);
  k_softmax<<<16384,256,0,stream>>>(SC);
  k_pv<<<dim3(2,16,16),256,0,stream>>>(SC, QKV, O2b);
  k_wo<<<dim3(16,16),256,0,stream>>>(O2b, WOD, hidden, Hb);
  k_rms<<<2048,256,0,stream>>>(Hb, g2, XN, HNB);
  k_router<<<512,256,0,stream>>>(XN, wg, CNT, TOK, WTS);
  k_moe_gemm1<<<dim3(32,28,4),256,0,stream>>>(HNB, W1Q, W3Q, CNT, TOK, UP, 0);
  k_moe_gemm2<<<dim3(32,8,4),256,0,stream>>>(UP, W2Q, CNT, TOK, WTS, MA, MB, 0);
  k_moe_gemm1<<<dim3(32,28,4),256,0,stream>>>(HNB, W1Q, W3Q, CNT, TOK, UP, 4);
  k_moe_gemm2<<<dim3(32,8,4),256,0,stream>>>(UP, W2Q, CNT, TOK, WTS, MA, MB, 4);
  k_final<<<2048,256,0,stream>>>(Hb, MA, MB, out);
}

// Round 3
// 1269.814 us; speedup vs baseline: 1.1437x; 1.1437x over previous
//
#include <hip/hip_runtime.h>
#include <hip/hip_bf16.h>

// QMixtralDecoderLayer: B=2 S=1024 D=1024 H=8 KVH=2 HD=128 E=8 TOPK=2 FFN=3584
// int4 group fake-quant (GS=128), RoPE theta=1e6, RMS eps=1e-5.
// Strategy: attention path f32 (router stability), MoE in bf16 MFMA.
// R2: MoE GEMMs -> 128x128 tiles, double-buffered LDS, n-major grid (dead m-tiles at tail).

typedef __attribute__((ext_vector_type(4))) float f32x4;
typedef __attribute__((ext_vector_type(8))) short short8;
typedef __hip_bfloat16 bf16;

#define DEV static __device__ __forceinline__

DEV float wsum(float v){
  #pragma unroll
  for (int o=32;o>0;o>>=1) v += __shfl_xor(v,o,64);
  return v;
}
DEV float wmaxr(float v){
  #pragma unroll
  for (int o=32;o>0;o>>=1) v = fmaxf(v,__shfl_xor(v,o,64));
  return v;
}
DEV float wminr(float v){
  #pragma unroll
  for (int o=32;o>0;o>>=1) v = fminf(v,__shfl_xor(v,o,64));
  return v;
}
// matches: (clip(round(x/s)+b,0,15)-b)*s with round-half-even
DEV float fakeq(float x, float s, float b){
  return (fminf(fmaxf(rintf(x/s)+b,0.f),15.f)-b)*s;
}

// ---------------- workspace layout (bytes) ----------------
constexpr size_t OFF_WQKV = 0;                         // 1536*1024 f32 (dequant wq|wk|wv)
constexpr size_t OFF_WO   = OFF_WQKV + 6291456;        // 1024*1024 f32
constexpr size_t OFF_W1Q  = OFF_WO   + 4194304;        // 8*3584*1024 bf16
constexpr size_t OFF_W3Q  = OFF_W1Q  + 58720256;
constexpr size_t OFF_W2Q  = OFF_W3Q  + 58720256;
constexpr size_t OFF_QKV  = OFF_W2Q  + 58720256;       // 2048*1536 f32
constexpr size_t OFF_SC   = OFF_QKV  + 12582912;       // 16*1024*1024 f32; later UP 4*2048*3584 bf16
constexpr size_t OFF_O2   = OFF_SC   + 67108864;       // 2048*1024 f32
constexpr size_t OFF_H    = OFF_O2   + 8388608;        // 2048*1024 f32
constexpr size_t OFF_XN   = OFF_H    + 8388608;        // xn then hn (f32)
constexpr size_t OFF_HNB  = OFF_XN   + 8388608;        // hn bf16
constexpr size_t OFF_COS  = OFF_HNB  + 4194304;        // 1024*64 f32
constexpr size_t OFF_SIN  = OFF_COS  + 262144;
constexpr size_t OFF_CNT  = OFF_SIN  + 262144;         // 8 ints (+pad)
constexpr size_t OFF_TOK  = OFF_CNT  + 256;            // 8*2048 int
constexpr size_t OFF_WTS  = OFF_TOK  + 65536;          // 8*2048 f32
constexpr size_t OFF_MA   = OFF_WTS  + 65536;          // 2048*1024 f32
constexpr size_t OFF_MB   = OFF_MA   + 8388608;
constexpr size_t WS_NEED  = OFF_MB   + 8388608;        // ~299 MB

__global__ void k_sentinel(float* out){ out[0] = 12345.0f; }
__global__ void k_zero(int* cnt){ if (threadIdx.x < 8) cnt[threadIdx.x] = 0; }

// ---------------- RMSNorm (f32 in, f32 out + optional bf16 out) ----------------
__global__ __launch_bounds__(256) void k_rms(const float* __restrict__ x,
                                             const float* __restrict__ g,
                                             float* __restrict__ out,
                                             bf16* __restrict__ outb)
{
  int row = blockIdx.x, tid = threadIdx.x;
  const float4* x4 = (const float4*)(x + (size_t)row*1024);
  float4 v = x4[tid];
  float ss = v.x*v.x + v.y*v.y + v.z*v.z + v.w*v.w;
  int lane = tid & 63, wv = tid >> 6;
  ss = wsum(ss);
  __shared__ float red[4];
  if (lane == 0) red[wv] = ss;
  __syncthreads();
  float tot = red[0]+red[1]+red[2]+red[3];
  float r = 1.0f / sqrtf(tot * (1.0f/1024.0f) + 1e-5f);
  float4 gg = ((const float4*)g)[tid];
  float4 o;
  o.x = v.x*r*gg.x; o.y = v.y*r*gg.y; o.z = v.z*r*gg.z; o.w = v.w*r*gg.w;
  ((float4*)(out + (size_t)row*1024))[tid] = o;
  if (outb) {
    bf16* ob = outb + (size_t)row*1024 + tid*4;
    ob[0]=__float2bfloat16(o.x); ob[1]=__float2bfloat16(o.y);
    ob[2]=__float2bfloat16(o.z); ob[3]=__float2bfloat16(o.w);
  }
}

// ---------------- weight dequant: attention (f32 out) ----------------
__global__ __launch_bounds__(256) void k_dequant_attn(
    const float* __restrict__ wq, const float* __restrict__ wk,
    const float* __restrict__ wv, const float* __restrict__ wo,
    float* __restrict__ wqkv, float* __restrict__ wod)
{
  int g = blockIdx.x*4 + (threadIdx.x>>6);
  int lane = threadIdx.x & 63;
  const float* src; float* dst;
  if (g < 8192)       { size_t o=(size_t)g*128;          src = wq + o; dst = wqkv + o; }
  else if (g < 10240) { size_t o=(size_t)(g-8192)*128;   src = wk + o; dst = wqkv + (size_t)1024*1024 + o; }
  else if (g < 12288) { size_t o=(size_t)(g-10240)*128;  src = wv + o; dst = wqkv + (size_t)1280*1024 + o; }
  else                { size_t o=(size_t)(g-12288)*128;  src = wo + o; dst = wod + o; }
  float x0 = src[lane], x1 = src[lane+64];
  float mn = wminr(fminf(x0,x1));
  float mx = wmaxr(fmaxf(x0,x1));
  float s = fmaxf(mx-mn, 1e-5f) / 15.0f;
  float b = fminf(fmaxf(rintf(-mn/s),0.f),15.f);
  dst[lane]    = fakeq(x0,s,b);
  dst[lane+64] = fakeq(x1,s,b);
}

// ---------------- weight dequant: MoE (bf16 out) ----------------
__global__ __launch_bounds__(256) void k_dequant_moe(
    const float* __restrict__ w1, const float* __restrict__ w3,
    const float* __restrict__ w2,
    bf16* __restrict__ o1, bf16* __restrict__ o3, bf16* __restrict__ o2q)
{
  int g = blockIdx.x*4 + (threadIdx.x>>6);  // 0..688127
  int lane = threadIdx.x & 63;
  const int NG = 229376;                    // 8*3584*1024/128
  int t = g / NG, gl = g - t*NG;
  const float* src; bf16* dst;
  if (t == 0)      { src = w1; dst = o1; }
  else if (t == 1) { src = w3; dst = o3; }
  else             { src = w2; dst = o2q; }
  src += (size_t)gl*128; dst += (size_t)gl*128;
  float x0 = src[lane], x1 = src[lane+64];
  float mn = wminr(fminf(x0,x1));
  float mx = wmaxr(fmaxf(x0,x1));
  float s = fmaxf(mx-mn, 1e-5f) / 15.0f;
  float b = fminf(fmaxf(rintf(-mn/s),0.f),15.f);
  dst[lane]    = __float2bfloat16(fakeq(x0,s,b));
  dst[lane+64] = __float2bfloat16(fakeq(x1,s,b));
}

// ---------------- RoPE tables ----------------
__global__ __launch_bounds__(256) void k_rope_tab(float* ct, float* st)
{
  int s = blockIdx.x*4 + (threadIdx.x>>6);
  int l = threadIdx.x & 63;
  float inv = 1.0f / powf(1.0e6f, (float)l * (1.0f/64.0f));
  float f = (float)s * inv;
  ct[s*64 + l] = cosf(f);
  st[s*64 + l] = sinf(f);
}

// ---------------- f32 GEMM core: C[M,N] = A[M,K] * B[N,K]^T (tile 128x64) ----------------
DEV void gemm_bt_128x64(const float* __restrict__ A, int lda,
                        const float* __restrict__ Bm, int ldb,
                        float* __restrict__ C, int ldc,
                        const float* __restrict__ resid,
                        int K, float scale, int m0, int n0)
{
  __shared__ float As[16*136];
  __shared__ float Bs[16*72];
  int tid = threadIdx.x;
  int ar = tid >> 1, ak = (tid & 1) * 8;
  int br = tid >> 2, bk = (tid & 3) * 4;
  const float* ap = A + (size_t)(m0 + ar)*lda + ak;
  const float* bp = Bm + (size_t)(n0 + br)*ldb + bk;
  int ty = tid >> 4, tx = tid & 15;
  int r0 = ty*8, c0 = tx*4;
  float acc[8][4];
  #pragma unroll
  for (int i=0;i<8;i++){
    #pragma unroll
    for (int j=0;j<4;j++) acc[i][j]=0.f;
  }
  for (int k0 = 0; k0 < K; k0 += 16) {
    float4 a0 = *(const float4*)(ap + k0);
    float4 a1 = *(const float4*)(ap + k0 + 4);
    float4 b0 = *(const float4*)(bp + k0);
    __syncthreads();
    As[(ak+0)*136+ar]=a0.x; As[(ak+1)*136+ar]=a0.y; As[(ak+2)*136+ar]=a0.z; As[(ak+3)*136+ar]=a0.w;
    As[(ak+4)*136+ar]=a1.x; As[(ak+5)*136+ar]=a1.y; As[(ak+6)*136+ar]=a1.z; As[(ak+7)*136+ar]=a1.w;
    Bs[(bk+0)*72+br]=b0.x;  Bs[(bk+1)*72+br]=b0.y;  Bs[(bk+2)*72+br]=b0.z;  Bs[(bk+3)*72+br]=b0.w;
    __syncthreads();
    #pragma unroll
    for (int kk = 0; kk < 16; kk++) {
      float4 xa = *(const float4*)&As[kk*136 + r0];
      float4 xb = *(const float4*)&As[kk*136 + r0 + 4];
      float4 yb = *(const float4*)&Bs[kk*72 + c0];
      float xs[8] = {xa.x,xa.y,xa.z,xa.w,xb.x,xb.y,xb.z,xb.w};
      float ys[4] = {yb.x,yb.y,yb.z,yb.w};
      #pragma unroll
      for (int i=0;i<8;i++){
        #pragma unroll
        for (int j=0;j<4;j++) acc[i][j] += xs[i]*ys[j];
      }
    }
  }
  #pragma unroll
  for (int i=0;i<8;i++){
    size_t ro = (size_t)(m0 + r0 + i)*ldc + n0 + c0;
    #pragma unroll
    for (int j=0;j<4;j++){
      float v = acc[i][j]*scale;
      if (resid) v += resid[ro + j];
      C[ro + j] = v;
    }
  }
}

__global__ __launch_bounds__(256) void k_qkv_gemm(const float* xn, const float* wqkv, float* qkv){
  gemm_bt_128x64(xn, 1024, wqkv, 1024, qkv, 1536, nullptr, 1024, 1.0f,
                 blockIdx.y*128, blockIdx.x*64);
}
__global__ __launch_bounds__(256) void k_wo(const float* o2, const float* wod,
                                            const float* hidden, float* h){
  gemm_bt_128x64(o2, 1024, wod, 1024, h, 1024, hidden, 1024, 1.0f,
                 blockIdx.y*128, blockIdx.x*64);
}
__global__ __launch_bounds__(256) void k_scores(const float* qkv, float* sc){
  int z = blockIdx.z, b = z >> 3, h = z & 7;
  int m0 = blockIdx.y*128, n0 = blockIdx.x*64;
  if (n0 > m0 + 127) return;   // fully-masked causal tile
  const float* A  = qkv + (size_t)b*1024*1536 + h*128;
  const float* Bp = qkv + (size_t)b*1024*1536 + 1024 + (h>>2)*128;
  float* C = sc + (size_t)z*1024*1024;
  gemm_bt_128x64(A, 1536, Bp, 1536, C, 1024, nullptr, 128, 0.08838834764831845f, m0, n0);
}

// ---------------- f32 GEMM core: C = A[M,K]*B[K,N] (tile 64x64), for attn@V ----------------
DEV void gemm_nn_64x64(const float* __restrict__ A, int lda,
                       const float* __restrict__ Bm, int ldb,
                       float* __restrict__ C, int ldc,
                       int kmax, int m0, int n0)
{
  __shared__ float As[16*68];
  __shared__ float Bs[16*68];
  int tid = threadIdx.x;
  int ar = tid >> 2, ak = (tid & 3)*4;
  int bk = tid >> 4, bc = (tid & 15)*4;
  const float* ap = A + (size_t)(m0 + ar)*lda + ak;
  const float* bp = Bm + (size_t)bk*ldb + n0 + bc;
  int ty = tid >> 4, tx = tid & 15;
  int r0 = ty*4, c0 = tx*4;
  float acc[4][4];
  #pragma unroll
  for (int i=0;i<4;i++){
    #pragma unroll
    for (int j=0;j<4;j++) acc[i][j]=0.f;
  }
  for (int k0 = 0; k0 < kmax; k0 += 16) {
    float4 a = *(const float4*)(ap + k0);
    float4 b = *(const float4*)(bp + (size_t)k0*ldb);
    __syncthreads();
    As[(ak+0)*68+ar]=a.x; As[(ak+1)*68+ar]=a.y; As[(ak+2)*68+ar]=a.z; As[(ak+3)*68+ar]=a.w;
    *(float4*)&Bs[bk*68 + bc] = b;
    __syncthreads();
    #pragma unroll
    for (int kk = 0; kk < 16; kk++) {
      float4 xa = *(const float4*)&As[kk*68 + r0];
      float4 yb = *(const float4*)&Bs[kk*68 + c0];
      float xs[4] = {xa.x,xa.y,xa.z,xa.w};
      float ys[4] = {yb.x,yb.y,yb.z,yb.w};
      #pragma unroll
      for (int i=0;i<4;i++){
        #pragma unroll
        for (int j=0;j<4;j++) acc[i][j] += xs[i]*ys[j];
      }
    }
  }
  #pragma unroll
  for (int i=0;i<4;i++){
    size_t ro = (size_t)(m0 + r0 + i)*ldc + n0 + c0;
    #pragma unroll
    for (int j=0;j<4;j++) C[ro + j] = acc[i][j];
  }
}

__global__ __launch_bounds__(256) void k_pv(const float* sc, const float* qkv, float* o2){
  int z = blockIdx.z, b = z >> 3, h = z & 7;
  int m0 = blockIdx.y*64, n0 = blockIdx.x*64;
  const float* A  = sc + (size_t)z*1024*1024;
  const float* Bp = qkv + (size_t)b*1024*1536 + 1280 + (h>>2)*128;
  float* C = o2 + (size_t)b*1024*1024 + h*128;
  gemm_nn_64x64(A, 1024, Bp, 1536, C, 1024, m0 + 64 /*causal kmax*/, m0, n0);
}

// ---------------- RoPE q (in-place in qkv) ----------------
__global__ __launch_bounds__(256) void k_rope_q(float* qkv, const float* ct, const float* st){
  int wid = blockIdx.x*4 + (threadIdx.x>>6);   // 0..16383
  int lane = threadIdx.x & 63;
  int t = wid >> 3, h = wid & 7;
  int s = t & 1023;
  float* base = qkv + (size_t)t*1536 + h*128;
  float x0 = base[lane], x1 = base[lane+64];
  float c = ct[s*64+lane], sn = st[s*64+lane];
  base[lane]    = x0*c - x1*sn;
  base[lane+64] = x1*c + x0*sn;
}

// ---------------- k: fake-quant then RoPE; v: fake-quant (in-place) ----------------
__global__ __launch_bounds__(256) void k_kv(float* qkv, const float* ct, const float* st){
  int wid = blockIdx.x*4 + (threadIdx.x>>6);   // 0..4095
  int lane = threadIdx.x & 63;
  int t = wid >> 1, kvh = wid & 1;
  int s = t & 1023;
  float* kb = qkv + (size_t)t*1536 + 1024 + kvh*128;
  float* vb = qkv + (size_t)t*1536 + 1280 + kvh*128;
  float k0v = kb[lane], k1v = kb[lane+64];
  float v0v = vb[lane], v1v = vb[lane+64];
  float mn = wminr(fminf(k0v,k1v));
  float mx = wmaxr(fmaxf(k0v,k1v));
  float sc = fmaxf(mx-mn,1e-5f)/15.0f;
  float bs = fminf(fmaxf(rintf(-mn/sc),0.f),15.f);
  float kq0 = fakeq(k0v,sc,bs), kq1 = fakeq(k1v,sc,bs);
  float c = ct[s*64+lane], sn = st[s*64+lane];
  kb[lane]    = kq0*c - kq1*sn;
  kb[lane+64] = kq1*c + kq0*sn;
  mn = wminr(fminf(v0v,v1v));
  mx = wmaxr(fmaxf(v0v,v1v));
  sc = fmaxf(mx-mn,1e-5f)/15.0f;
  bs = fminf(fmaxf(rintf(-mn/sc),0.f),15.f);
  vb[lane]    = fakeq(v0v,sc,bs);
  vb[lane+64] = fakeq(v1v,sc,bs);
}

// ---------------- causal softmax over scores rows (in-place) ----------------
__global__ __launch_bounds__(256) void k_softmax(float* sc){
  int row = blockIdx.x;                 // 16384 = 16*1024
  int i = row & 1023;                   // query position
  float* p = sc + (size_t)row*1024;
  int tid = threadIdx.x, lane = tid & 63, wv = tid >> 6;
  float v[4];
  float m = -3.0e38f;
  #pragma unroll
  for (int k2=0;k2<4;k2++){
    int j = tid + k2*256;
    v[k2] = p[j];
    if (j <= i) m = fmaxf(m, v[k2]);
  }
  __shared__ float red[4];
  m = wmaxr(m);
  if (lane==0) red[wv] = m;
  __syncthreads();
  m = fmaxf(fmaxf(red[0],red[1]), fmaxf(red[2],red[3]));
  float ls = 0.f;
  #pragma unroll
  for (int k2=0;k2<4;k2++){
    int j = tid + k2*256;
    float e = (j <= i) ? __expf(v[k2]-m) : 0.0f;
    v[k2] = e; ls += e;
  }
  __syncthreads();
  ls = wsum(ls);
  if (lane==0) red[wv] = ls;
  __syncthreads();
  float inv = 1.0f / (red[0]+red[1]+red[2]+red[3]);
  #pragma unroll
  for (int k2=0;k2<4;k2++){
    int j = tid + k2*256;
    p[j] = v[k2]*inv;
  }
}

// ---------------- router: logits, softmax, stable top-2, scatter ----------------
__global__ __launch_bounds__(256) void k_router(const float* __restrict__ hn,
                                                const float* __restrict__ wg,
                                                int* cnt, int* toksl, float* wts){
  int t = blockIdx.x*4 + (threadIdx.x>>6);
  int lane = threadIdx.x & 63;
  const float* x = hn + (size_t)t*1024;
  float p[8];
  #pragma unroll
  for (int e=0;e<8;e++) p[e]=0.f;
  for (int i=0;i<16;i++){
    float xv = x[lane + i*64];
    #pragma unroll
    for (int e=0;e<8;e++) p[e] += xv * wg[e*1024 + lane + i*64];
  }
  #pragma unroll
  for (int e=0;e<8;e++) p[e] = wsum(p[e]);
  if (lane==0){
    float m = p[0];
    for (int e=1;e<8;e++) m = fmaxf(m,p[e]);
    float ex[8], sum=0.f;
    for (int e=0;e<8;e++){ ex[e]=__expf(p[e]-m); sum+=ex[e]; }
    float pr[8];
    for (int e=0;e<8;e++) pr[e]=ex[e]/sum;
    int i1 = 0;
    for (int e=1;e<8;e++) if (pr[e] > pr[i1]) i1 = e;   // ties -> lowest idx (stable)
    int i2 = -1;
    for (int e=0;e<8;e++){ if (e==i1) continue; if (i2<0 || pr[e] > pr[i2]) i2 = e; }
    float ssum = pr[i1]+pr[i2];
    float wa = pr[i1]/ssum, wb = pr[i2]/ssum;
    int pos = atomicAdd(cnt+i1,1);
    toksl[i1*2048+pos] = t;          wts[i1*2048+pos] = wa;
    pos = atomicAdd(cnt+i2,1);
    toksl[i2*2048+pos] = t | 65536;  wts[i2*2048+pos] = wb;
  }
}

// ---------------- MoE GEMM1 v2: up = silu(hn@w1^T) * (hn@w3^T) ----------------
// tile 128(tokens) x 128(ffn) dual-B, K=1024, BK=32, double-buffered LDS.
// grid: x = n-tile (padded to 32 for XCD clustering), y = m-tile (16), z = expert-local (4)
__global__ __launch_bounds__(256) void k_moe_gemm1(
    const bf16* __restrict__ hnb, const bf16* __restrict__ w1q, const bf16* __restrict__ w3q,
    const int* __restrict__ cnt, const int* __restrict__ toksl,
    bf16* __restrict__ up, int ebase)
{
  int n0 = blockIdx.x * 128;
  if (n0 >= 3584) return;                       // x padded 28->32
  int el = blockIdx.z, e = ebase + el;
  int c = cnt[e];
  int m0 = blockIdx.y * 128;
  if (m0 >= c) return;
  __shared__ bf16 As[2][128*40];
  __shared__ bf16 B1s[2][128*40];
  __shared__ bf16 B3s[2][128*40];
  int tid = threadIdx.x, lane = tid & 63, wv = tid >> 6;
  int arow = tid >> 1, acol = (tid & 1) * 16;   // each thread: 1 row, 16 K-elems (2x short8)
  int slot = m0 + arow;
  int tok = (slot < c) ? (toksl[e*2048 + slot] & 0xFFFF) : 0;
  const bf16* ap  = hnb + (size_t)tok*1024 + acol;
  const bf16* b1p = w1q + ((size_t)e*3584 + n0 + arow)*1024 + acol;
  const bf16* b3p = w3q + ((size_t)e*3584 + n0 + arow)*1024 + acol;
  int mq = wv & 1, nq = wv >> 1;                // wave sub-tile: 64x64
  int fr = lane & 15, fq = lane >> 4;
  f32x4 zero = {0.f,0.f,0.f,0.f};
  f32x4 acc1[4][4], acc3[4][4];
  #pragma unroll
  for (int i=0;i<4;i++){
    #pragma unroll
    for (int j=0;j<4;j++){ acc1[i][j]=zero; acc3[i][j]=zero; }
  }
  // prologue: stage k=0 into buf 0
  short8 a0 = *(const short8*)(ap);
  short8 a1 = *(const short8*)(ap + 8);
  short8 p0 = *(const short8*)(b1p);
  short8 p1 = *(const short8*)(b1p + 8);
  short8 q0 = *(const short8*)(b3p);
  short8 q1 = *(const short8*)(b3p + 8);
  *(short8*)&As[0][arow*40 + acol]      = a0;
  *(short8*)&As[0][arow*40 + acol + 8]  = a1;
  *(short8*)&B1s[0][arow*40 + acol]     = p0;
  *(short8*)&B1s[0][arow*40 + acol + 8] = p1;
  *(short8*)&B3s[0][arow*40 + acol]     = q0;
  *(short8*)&B3s[0][arow*40 + acol + 8] = q1;
  int buf = 0;
  for (int k0 = 0; k0 < 1024; k0 += 32) {
    __syncthreads();
    bool more = (k0 + 32) < 1024;
    if (more) {
      a0 = *(const short8*)(ap + k0 + 32);
      a1 = *(const short8*)(ap + k0 + 40);
      p0 = *(const short8*)(b1p + k0 + 32);
      p1 = *(const short8*)(b1p + k0 + 40);
      q0 = *(const short8*)(b3p + k0 + 32);
      q1 = *(const short8*)(b3p + k0 + 40);
    }
    short8 aF[4];
    #pragma unroll
    for (int mt=0; mt<4; mt++)
      aF[mt] = *(const short8*)&As[buf][(mq*64 + mt*16 + fr)*40 + fq*8];
    #pragma unroll
    for (int nt=0; nt<4; nt++){
      short8 b1F = *(const short8*)&B1s[buf][(nq*64 + nt*16 + fr)*40 + fq*8];
      short8 b3F = *(const short8*)&B3s[buf][(nq*64 + nt*16 + fr)*40 + fq*8];
      #pragma unroll
      for (int mt=0; mt<4; mt++){
        acc1[mt][nt] = __builtin_amdgcn_mfma_f32_16x16x32_bf16(aF[mt], b1F, acc1[mt][nt], 0,0,0);
        acc3[mt][nt] = __builtin_amdgcn_mfma_f32_16x16x32_bf16(aF[mt], b3F, acc3[mt][nt], 0,0,0);
      }
    }
    if (more) {
      __syncthreads();
      int nb = buf ^ 1;
      *(short8*)&As[nb][arow*40 + acol]      = a0;
      *(short8*)&As[nb][arow*40 + acol + 8]  = a1;
      *(short8*)&B1s[nb][arow*40 + acol]     = p0;
      *(short8*)&B1s[nb][arow*40 + acol + 8] = p1;
      *(short8*)&B3s[nb][arow*40 + acol]     = q0;
      *(short8*)&B3s[nb][arow*40 + acol + 8] = q1;
      buf = nb;
    }
  }
  bf16* upb = up + (size_t)el*2048*3584;
  #pragma unroll
  for (int mt=0; mt<4; mt++){
    #pragma unroll
    for (int nt=0; nt<4; nt++){
      #pragma unroll
      for (int r=0; r<4; r++){
        int srow = m0 + mq*64 + mt*16 + fq*4 + r;   // C layout: row=(lane>>4)*4+reg
        int fcol = n0 + nq*64 + nt*16 + fr;         //           col=lane&15
        float x1 = acc1[mt][nt][r], x3 = acc3[mt][nt][r];
        float u = (x1 / (1.0f + __expf(-x1))) * x3;
        upb[(size_t)srow*3584 + fcol] = __float2bfloat16(u);
      }
    }
  }
}

// ---------------- MoE GEMM2 v2: moe = wt * (up @ w2^T) ----------------
// tile 128 x 128, K=3584, BK=32, double-buffered. grid: x=n(8), y=m(16), z=e(4)
__global__ __launch_bounds__(256) void k_moe_gemm2(
    const bf16* __restrict__ up, const bf16* __restrict__ w2q,
    const int* __restrict__ cnt, const int* __restrict__ toksl,
    const float* __restrict__ wts,
    float* __restrict__ moeA, float* __restrict__ moeB, int ebase)
{
  int el = blockIdx.z, e = ebase + el;
  int c = cnt[e];
  int m0 = blockIdx.y * 128;
  if (m0 >= c) return;
  int n0 = blockIdx.x * 128;
  __shared__ bf16 As[2][128*40];
  __shared__ bf16 Bs[2][128*40];
  int tid = threadIdx.x, lane = tid & 63, wv = tid >> 6;
  int arow = tid >> 1, acol = (tid & 1) * 16;
  const bf16* ap = up + (size_t)el*2048*3584 + (size_t)(m0 + arow)*3584 + acol;
  const bf16* bp = w2q + ((size_t)e*1024 + n0 + arow)*3584 + acol;
  int mq = wv & 1, nq = wv >> 1;
  int fr = lane & 15, fq = lane >> 4;
  f32x4 zero = {0.f,0.f,0.f,0.f};
  f32x4 acc[4][4];
  #pragma unroll
  for (int i=0;i<4;i++){
    #pragma unroll
    for (int j=0;j<4;j++) acc[i][j]=zero;
  }
  short8 a0 = *(const short8*)(ap);
  short8 a1 = *(const short8*)(ap + 8);
  short8 b0 = *(const short8*)(bp);
  short8 b1 = *(const short8*)(bp + 8);
  *(short8*)&As[0][arow*40 + acol]     = a0;
  *(short8*)&As[0][arow*40 + acol + 8] = a1;
  *(short8*)&Bs[0][arow*40 + acol]     = b0;
  *(short8*)&Bs[0][arow*40 + acol + 8] = b1;
  int buf = 0;
  for (int k0 = 0; k0 < 3584; k0 += 32) {
    __syncthreads();
    bool more = (k0 + 32) < 3584;
    if (more) {
      a0 = *(const short8*)(ap + k0 + 32);
      a1 = *(const short8*)(ap + k0 + 40);
      b0 = *(const short8*)(bp + k0 + 32);
      b1 = *(const short8*)(bp + k0 + 40);
    }
    short8 aF[4];
    #pragma unroll
    for (int mt=0; mt<4; mt++)
      aF[mt] = *(const short8*)&As[buf][(mq*64 + mt*16 + fr)*40 + fq*8];
    #pragma unroll
    for (int nt=0; nt<4; nt++){
      short8 bF = *(const short8*)&Bs[buf][(nq*64 + nt*16 + fr)*40 + fq*8];
      #pragma unroll
      for (int mt=0; mt<4; mt++)
        acc[mt][nt] = __builtin_amdgcn_mfma_f32_16x16x32_bf16(aF[mt], bF, acc[mt][nt], 0,0,0);
    }
    if (more) {
      __syncthreads();
      int nb = buf ^ 1;
      *(short8*)&As[nb][arow*40 + acol]     = a0;
      *(short8*)&As[nb][arow*40 + acol + 8] = a1;
      *(short8*)&Bs[nb][arow*40 + acol]     = b0;
      *(short8*)&Bs[nb][arow*40 + acol + 8] = b1;
      buf = nb;
    }
  }
  #pragma unroll
  for (int mt=0; mt<4; mt++){
    #pragma unroll
    for (int nt=0; nt<4; nt++){
      #pragma unroll
      for (int r=0; r<4; r++){
        int srow = m0 + mq*64 + mt*16 + fq*4 + r;
        if (srow < c){
          int ts = toksl[e*2048 + srow];
          int tok = ts & 0xFFFF, fl = ts >> 16;
          float wt = wts[e*2048 + srow];
          int d = n0 + nq*64 + nt*16 + fr;
          float* dst = (fl ? moeB : moeA) + (size_t)tok*1024 + d;
          *dst = acc[mt][nt][r] * wt;
        }
      }
    }
  }
}

// ---------------- final: out = h + moeA + moeB ----------------
__global__ __launch_bounds__(256) void k_final(const float* h, const float* ma,
                                               const float* mb, float* out){
  size_t i = (size_t)blockIdx.x*256 + threadIdx.x;
  float4 a = ((const float4*)h)[i];
  float4 b = ((const float4*)ma)[i];
  float4 c = ((const float4*)mb)[i];
  float4 o;
  o.x = a.x+b.x+c.x; o.y = a.y+b.y+c.y; o.z = a.z+b.z+c.z; o.w = a.w+b.w+c.w;
  ((float4*)out)[i] = o;
}

extern "C" void kernel_launch(void* const* d_in, const int* in_sizes, int n_in,
                              void* d_out, int out_size, void* d_ws, size_t ws_size,
                              hipStream_t stream)
{
  (void)in_sizes; (void)n_in; (void)out_size;
  float* out = (float*)d_out;
  if (ws_size < WS_NEED) { k_sentinel<<<1,1,0,stream>>>(out); return; } // ws too small -> absmax ~12345 marker

  const float* hidden = (const float*)d_in[0];
  const float* w_q  = (const float*)d_in[1];
  const float* w_k  = (const float*)d_in[2];
  const float* w_v  = (const float*)d_in[3];
  const float* w_o  = (const float*)d_in[4];
  const float* g1   = (const float*)d_in[5];
  const float* g2   = (const float*)d_in[6];
  const float* wg   = (const float*)d_in[7];
  const float* w1   = (const float*)d_in[8];
  const float* w3   = (const float*)d_in[9];
  const float* w2   = (const float*)d_in[10];
  char* ws = (char*)d_ws;
  float* WQKV = (float*)(ws + OFF_WQKV);
  float* WOD  = (float*)(ws + OFF_WO);
  bf16*  W1Q  = (bf16*)(ws + OFF_W1Q);
  bf16*  W3Q  = (bf16*)(ws + OFF_W3Q);
  bf16*  W2Q  = (bf16*)(ws + OFF_W2Q);
  float* QKV  = (float*)(ws + OFF_QKV);
  float* SC   = (float*)(ws + OFF_SC);
  bf16*  UP   = (bf16*)(ws + OFF_SC);    // aliases SC (scores dead before MoE)
  float* O2b  = (float*)(ws + OFF_O2);
  float* Hb   = (float*)(ws + OFF_H);
  float* XN   = (float*)(ws + OFF_XN);   // xn, later hn (f32)
  bf16*  HNB  = (bf16*)(ws + OFF_HNB);
  float* CT   = (float*)(ws + OFF_COS);
  float* ST   = (float*)(ws + OFF_SIN);
  int*   CNT  = (int*)(ws + OFF_CNT);
  int*   TOK  = (int*)(ws + OFF_TOK);
  float* WTS  = (float*)(ws + OFF_WTS);
  float* MA   = (float*)(ws + OFF_MA);
  float* MB   = (float*)(ws + OFF_MB);

  k_zero<<<1,64,0,stream>>>(CNT);
  k_rms<<<2048,256,0,stream>>>(hidden, g1, XN, (bf16*)nullptr);
  k_dequant_attn<<<5120,256,0,stream>>>(w_q, w_k, w_v, w_o, WQKV, WOD);
  k_dequant_moe<<<172032,256,0,stream>>>(w1, w3, w2, W1Q, W3Q, W2Q);
  k_rope_tab<<<256,256,0,stream>>>(CT, ST);
  k_qkv_gemm<<<dim3(24,16),256,0,stream>>>(XN, WQKV, QKV);
  k_rope_q<<<4096,256,0,stream>>>(QKV, CT, ST);
  k_kv<<<1024,256,0,stream>>>(QKV, CT, ST);
  k_scores<<<dim3(16,8,16),256,0,stream>>>(QKV, SC);
  k_softmax<<<16384,256,0,stream>>>(SC);
  k_pv<<<dim3(2,16,16),256,0,stream>>>(SC, QKV, O2b);
  k_wo<<<dim3(16,16),256,0,stream>>>(O2b, WOD, hidden, Hb);
  k_rms<<<2048,256,0,stream>>>(Hb, g2, XN, HNB);
  k_router<<<512,256,0,stream>>>(XN, wg, CNT, TOK, WTS);
  k_moe_gemm1<<<dim3(32,16,4),256,0,stream>>>(HNB, W1Q, W3Q, CNT, TOK, UP, 0);
  k_moe_gemm2<<<dim3(8,16,4),256,0,stream>>>(UP, W2Q, CNT, TOK, WTS, MA, MB, 0);
  k_moe_gemm1<<<dim3(32,16,4),256,0,stream>>>(HNB, W1Q, W3Q, CNT, TOK, UP, 4);
  k_moe_gemm2<<<dim3(8,16,4),256,0,stream>>>(UP, W2Q, CNT, TOK, WTS, MA, MB, 4);
  k_final<<<2048,256,0,stream>>>(Hb, MA, MB, out);
}

// Round 4
// 1259.434 us; speedup vs baseline: 1.1531x; 1.0082x over previous
//
#include <hip/hip_runtime.h>
#include <hip/hip_bf16.h>

// QMixtralDecoderLayer: B=2 S=1024 D=1024 H=8 KVH=2 HD=128 E=8 TOPK=2 FFN=3584
// int4 group fake-quant (GS=128), RoPE theta=1e6, RMS eps=1e-5.
// Strategy: attention path f32 (router stability), MoE in bf16 MFMA.
// R2: MoE GEMMs -> 128x128 tiles, double-buffered LDS, n-major grid.
// R3: dequant kernels: hoist divisions (1/s once per group), float2 loads, packed stores.

typedef __attribute__((ext_vector_type(4))) float f32x4;
typedef __attribute__((ext_vector_type(8))) short short8;
typedef __hip_bfloat16 bf16;

#define DEV static __device__ __forceinline__

DEV float wsum(float v){
  #pragma unroll
  for (int o=32;o>0;o>>=1) v += __shfl_xor(v,o,64);
  return v;
}
DEV float wmaxr(float v){
  #pragma unroll
  for (int o=32;o>0;o>>=1) v = fmaxf(v,__shfl_xor(v,o,64));
  return v;
}
DEV float wminr(float v){
  #pragma unroll
  for (int o=32;o>0;o>>=1) v = fminf(v,__shfl_xor(v,o,64));
  return v;
}
// matches: (clip(round(x/s)+b,0,15)-b)*s with round-half-even; inv = 1/s hoisted
DEV float fakeq(float x, float s, float inv, float b){
  return (fminf(fmaxf(rintf(x*inv)+b,0.f),15.f)-b)*s;
}

// ---------------- workspace layout (bytes) ----------------
constexpr size_t OFF_WQKV = 0;                         // 1536*1024 f32 (dequant wq|wk|wv)
constexpr size_t OFF_WO   = OFF_WQKV + 6291456;        // 1024*1024 f32
constexpr size_t OFF_W1Q  = OFF_WO   + 4194304;        // 8*3584*1024 bf16
constexpr size_t OFF_W3Q  = OFF_W1Q  + 58720256;
constexpr size_t OFF_W2Q  = OFF_W3Q  + 58720256;
constexpr size_t OFF_QKV  = OFF_W2Q  + 58720256;       // 2048*1536 f32
constexpr size_t OFF_SC   = OFF_QKV  + 12582912;       // 16*1024*1024 f32; later UP 4*2048*3584 bf16
constexpr size_t OFF_O2   = OFF_SC   + 67108864;       // 2048*1024 f32
constexpr size_t OFF_H    = OFF_O2   + 8388608;        // 2048*1024 f32
constexpr size_t OFF_XN   = OFF_H    + 8388608;        // xn then hn (f32)
constexpr size_t OFF_HNB  = OFF_XN   + 8388608;        // hn bf16
constexpr size_t OFF_COS  = OFF_HNB  + 4194304;        // 1024*64 f32
constexpr size_t OFF_SIN  = OFF_COS  + 262144;
constexpr size_t OFF_CNT  = OFF_SIN  + 262144;         // 8 ints (+pad)
constexpr size_t OFF_TOK  = OFF_CNT  + 256;            // 8*2048 int
constexpr size_t OFF_WTS  = OFF_TOK  + 65536;          // 8*2048 f32
constexpr size_t OFF_MA   = OFF_WTS  + 65536;          // 2048*1024 f32
constexpr size_t OFF_MB   = OFF_MA   + 8388608;
constexpr size_t WS_NEED  = OFF_MB   + 8388608;        // ~299 MB

__global__ void k_sentinel(float* out){ out[0] = 12345.0f; }
__global__ void k_zero(int* cnt){ if (threadIdx.x < 8) cnt[threadIdx.x] = 0; }

// ---------------- RMSNorm (f32 in, f32 out + optional bf16 out) ----------------
__global__ __launch_bounds__(256) void k_rms(const float* __restrict__ x,
                                             const float* __restrict__ g,
                                             float* __restrict__ out,
                                             bf16* __restrict__ outb)
{
  int row = blockIdx.x, tid = threadIdx.x;
  const float4* x4 = (const float4*)(x + (size_t)row*1024);
  float4 v = x4[tid];
  float ss = v.x*v.x + v.y*v.y + v.z*v.z + v.w*v.w;
  int lane = tid & 63, wv = tid >> 6;
  ss = wsum(ss);
  __shared__ float red[4];
  if (lane == 0) red[wv] = ss;
  __syncthreads();
  float tot = red[0]+red[1]+red[2]+red[3];
  float r = 1.0f / sqrtf(tot * (1.0f/1024.0f) + 1e-5f);
  float4 gg = ((const float4*)g)[tid];
  float4 o;
  o.x = v.x*r*gg.x; o.y = v.y*r*gg.y; o.z = v.z*r*gg.z; o.w = v.w*r*gg.w;
  ((float4*)(out + (size_t)row*1024))[tid] = o;
  if (outb) {
    bf16* ob = outb + (size_t)row*1024 + tid*4;
    ob[0]=__float2bfloat16(o.x); ob[1]=__float2bfloat16(o.y);
    ob[2]=__float2bfloat16(o.z); ob[3]=__float2bfloat16(o.w);
  }
}

// ---------------- weight dequant: attention (f32 out) ----------------
// 1 wave per 128-elem group; lane holds elems {2l, 2l+1} via float2
__global__ __launch_bounds__(256) void k_dequant_attn(
    const float* __restrict__ wq, const float* __restrict__ wk,
    const float* __restrict__ wv, const float* __restrict__ wo,
    float* __restrict__ wqkv, float* __restrict__ wod)
{
  int g = blockIdx.x*4 + (threadIdx.x>>6);
  int lane = threadIdx.x & 63;
  const float* src; float* dst;
  if (g < 8192)       { size_t o=(size_t)g*128;          src = wq + o; dst = wqkv + o; }
  else if (g < 10240) { size_t o=(size_t)(g-8192)*128;   src = wk + o; dst = wqkv + (size_t)1024*1024 + o; }
  else if (g < 12288) { size_t o=(size_t)(g-10240)*128;  src = wv + o; dst = wqkv + (size_t)1280*1024 + o; }
  else                { size_t o=(size_t)(g-12288)*128;  src = wo + o; dst = wod + o; }
  float2 xv = *(const float2*)(src + 2*lane);
  float mn = wminr(fminf(xv.x,xv.y));
  float mx = wmaxr(fmaxf(xv.x,xv.y));
  float s = fmaxf(mx-mn, 1e-5f) / 15.0f;
  float inv = 1.0f / s;
  float b = fminf(fmaxf(rintf(-mn*inv),0.f),15.f);
  float2 o2;
  o2.x = fakeq(xv.x,s,inv,b);
  o2.y = fakeq(xv.y,s,inv,b);
  *(float2*)(dst + 2*lane) = o2;
}

// ---------------- weight dequant: MoE (bf16 out) ----------------
__global__ __launch_bounds__(256) void k_dequant_moe(
    const float* __restrict__ w1, const float* __restrict__ w3,
    const float* __restrict__ w2,
    bf16* __restrict__ o1, bf16* __restrict__ o3, bf16* __restrict__ o2q)
{
  int g = blockIdx.x*4 + (threadIdx.x>>6);  // 0..688127
  int lane = threadIdx.x & 63;
  const int NG = 229376;                    // 8*3584*1024/128
  int t = g / NG, gl = g - t*NG;
  const float* src; bf16* dst;
  if (t == 0)      { src = w1; dst = o1; }
  else if (t == 1) { src = w3; dst = o3; }
  else             { src = w2; dst = o2q; }
  src += (size_t)gl*128; dst += (size_t)gl*128;
  float2 xv = *(const float2*)(src + 2*lane);
  float mn = wminr(fminf(xv.x,xv.y));
  float mx = wmaxr(fmaxf(xv.x,xv.y));
  float s = fmaxf(mx-mn, 1e-5f) / 15.0f;
  float inv = 1.0f / s;
  float b = fminf(fmaxf(rintf(-mn*inv),0.f),15.f);
  __hip_bfloat162 pk;
  pk.x = __float2bfloat16(fakeq(xv.x,s,inv,b));
  pk.y = __float2bfloat16(fakeq(xv.y,s,inv,b));
  *(__hip_bfloat162*)(dst + 2*lane) = pk;
}

// ---------------- RoPE tables ----------------
__global__ __launch_bounds__(256) void k_rope_tab(float* ct, float* st)
{
  int s = blockIdx.x*4 + (threadIdx.x>>6);
  int l = threadIdx.x & 63;
  float inv = 1.0f / powf(1.0e6f, (float)l * (1.0f/64.0f));
  float f = (float)s * inv;
  ct[s*64 + l] = cosf(f);
  st[s*64 + l] = sinf(f);
}

// ---------------- f32 GEMM core: C[M,N] = A[M,K] * B[N,K]^T (tile 128x64) ----------------
DEV void gemm_bt_128x64(const float* __restrict__ A, int lda,
                        const float* __restrict__ Bm, int ldb,
                        float* __restrict__ C, int ldc,
                        const float* __restrict__ resid,
                        int K, float scale, int m0, int n0)
{
  __shared__ float As[16*136];
  __shared__ float Bs[16*72];
  int tid = threadIdx.x;
  int ar = tid >> 1, ak = (tid & 1) * 8;
  int br = tid >> 2, bk = (tid & 3) * 4;
  const float* ap = A + (size_t)(m0 + ar)*lda + ak;
  const float* bp = Bm + (size_t)(n0 + br)*ldb + bk;
  int ty = tid >> 4, tx = tid & 15;
  int r0 = ty*8, c0 = tx*4;
  float acc[8][4];
  #pragma unroll
  for (int i=0;i<8;i++){
    #pragma unroll
    for (int j=0;j<4;j++) acc[i][j]=0.f;
  }
  for (int k0 = 0; k0 < K; k0 += 16) {
    float4 a0 = *(const float4*)(ap + k0);
    float4 a1 = *(const float4*)(ap + k0 + 4);
    float4 b0 = *(const float4*)(bp + k0);
    __syncthreads();
    As[(ak+0)*136+ar]=a0.x; As[(ak+1)*136+ar]=a0.y; As[(ak+2)*136+ar]=a0.z; As[(ak+3)*136+ar]=a0.w;
    As[(ak+4)*136+ar]=a1.x; As[(ak+5)*136+ar]=a1.y; As[(ak+6)*136+ar]=a1.z; As[(ak+7)*136+ar]=a1.w;
    Bs[(bk+0)*72+br]=b0.x;  Bs[(bk+1)*72+br]=b0.y;  Bs[(bk+2)*72+br]=b0.z;  Bs[(bk+3)*72+br]=b0.w;
    __syncthreads();
    #pragma unroll
    for (int kk = 0; kk < 16; kk++) {
      float4 xa = *(const float4*)&As[kk*136 + r0];
      float4 xb = *(const float4*)&As[kk*136 + r0 + 4];
      float4 yb = *(const float4*)&Bs[kk*72 + c0];
      float xs[8] = {xa.x,xa.y,xa.z,xa.w,xb.x,xb.y,xb.z,xb.w};
      float ys[4] = {yb.x,yb.y,yb.z,yb.w};
      #pragma unroll
      for (int i=0;i<8;i++){
        #pragma unroll
        for (int j=0;j<4;j++) acc[i][j] += xs[i]*ys[j];
      }
    }
  }
  #pragma unroll
  for (int i=0;i<8;i++){
    size_t ro = (size_t)(m0 + r0 + i)*ldc + n0 + c0;
    #pragma unroll
    for (int j=0;j<4;j++){
      float v = acc[i][j]*scale;
      if (resid) v += resid[ro + j];
      C[ro + j] = v;
    }
  }
}

__global__ __launch_bounds__(256) void k_qkv_gemm(const float* xn, const float* wqkv, float* qkv){
  gemm_bt_128x64(xn, 1024, wqkv, 1024, qkv, 1536, nullptr, 1024, 1.0f,
                 blockIdx.y*128, blockIdx.x*64);
}
__global__ __launch_bounds__(256) void k_wo(const float* o2, const float* wod,
                                            const float* hidden, float* h){
  gemm_bt_128x64(o2, 1024, wod, 1024, h, 1024, hidden, 1024, 1.0f,
                 blockIdx.y*128, blockIdx.x*64);
}
__global__ __launch_bounds__(256) void k_scores(const float* qkv, float* sc){
  int z = blockIdx.z, b = z >> 3, h = z & 7;
  int m0 = blockIdx.y*128, n0 = blockIdx.x*64;
  if (n0 > m0 + 127) return;   // fully-masked causal tile
  const float* A  = qkv + (size_t)b*1024*1536 + h*128;
  const float* Bp = qkv + (size_t)b*1024*1536 + 1024 + (h>>2)*128;
  float* C = sc + (size_t)z*1024*1024;
  gemm_bt_128x64(A, 1536, Bp, 1536, C, 1024, nullptr, 128, 0.08838834764831845f, m0, n0);
}

// ---------------- f32 GEMM core: C = A[M,K]*B[K,N] (tile 64x64), for attn@V ----------------
DEV void gemm_nn_64x64(const float* __restrict__ A, int lda,
                       const float* __restrict__ Bm, int ldb,
                       float* __restrict__ C, int ldc,
                       int kmax, int m0, int n0)
{
  __shared__ float As[16*68];
  __shared__ float Bs[16*68];
  int tid = threadIdx.x;
  int ar = tid >> 2, ak = (tid & 3)*4;
  int bk = tid >> 4, bc = (tid & 15)*4;
  const float* ap = A + (size_t)(m0 + ar)*lda + ak;
  const float* bp = Bm + (size_t)bk*ldb + n0 + bc;
  int ty = tid >> 4, tx = tid & 15;
  int r0 = ty*4, c0 = tx*4;
  float acc[4][4];
  #pragma unroll
  for (int i=0;i<4;i++){
    #pragma unroll
    for (int j=0;j<4;j++) acc[i][j]=0.f;
  }
  for (int k0 = 0; k0 < kmax; k0 += 16) {
    float4 a = *(const float4*)(ap + k0);
    float4 b = *(const float4*)(bp + (size_t)k0*ldb);
    __syncthreads();
    As[(ak+0)*68+ar]=a.x; As[(ak+1)*68+ar]=a.y; As[(ak+2)*68+ar]=a.z; As[(ak+3)*68+ar]=a.w;
    *(float4*)&Bs[bk*68 + bc] = b;
    __syncthreads();
    #pragma unroll
    for (int kk = 0; kk < 16; kk++) {
      float4 xa = *(const float4*)&As[kk*68 + r0];
      float4 yb = *(const float4*)&Bs[kk*68 + c0];
      float xs[4] = {xa.x,xa.y,xa.z,xa.w};
      float ys[4] = {yb.x,yb.y,yb.z,yb.w};
      #pragma unroll
      for (int i=0;i<4;i++){
        #pragma unroll
        for (int j=0;j<4;j++) acc[i][j] += xs[i]*ys[j];
      }
    }
  }
  #pragma unroll
  for (int i=0;i<4;i++){
    size_t ro = (size_t)(m0 + r0 + i)*ldc + n0 + c0;
    #pragma unroll
    for (int j=0;j<4;j++) C[ro + j] = acc[i][j];
  }
}

__global__ __launch_bounds__(256) void k_pv(const float* sc, const float* qkv, float* o2){
  int z = blockIdx.z, b = z >> 3, h = z & 7;
  int m0 = blockIdx.y*64, n0 = blockIdx.x*64;
  const float* A  = sc + (size_t)z*1024*1024;
  const float* Bp = qkv + (size_t)b*1024*1536 + 1280 + (h>>2)*128;
  float* C = o2 + (size_t)b*1024*1024 + h*128;
  gemm_nn_64x64(A, 1024, Bp, 1536, C, 1024, m0 + 64 /*causal kmax*/, m0, n0);
}

// ---------------- RoPE q (in-place in qkv) ----------------
__global__ __launch_bounds__(256) void k_rope_q(float* qkv, const float* ct, const float* st){
  int wid = blockIdx.x*4 + (threadIdx.x>>6);   // 0..16383
  int lane = threadIdx.x & 63;
  int t = wid >> 3, h = wid & 7;
  int s = t & 1023;
  float* base = qkv + (size_t)t*1536 + h*128;
  float x0 = base[lane], x1 = base[lane+64];
  float c = ct[s*64+lane], sn = st[s*64+lane];
  base[lane]    = x0*c - x1*sn;
  base[lane+64] = x1*c + x0*sn;
}

// ---------------- k: fake-quant then RoPE; v: fake-quant (in-place) ----------------
__global__ __launch_bounds__(256) void k_kv(float* qkv, const float* ct, const float* st){
  int wid = blockIdx.x*4 + (threadIdx.x>>6);   // 0..4095
  int lane = threadIdx.x & 63;
  int t = wid >> 1, kvh = wid & 1;
  int s = t & 1023;
  float* kb = qkv + (size_t)t*1536 + 1024 + kvh*128;
  float* vb = qkv + (size_t)t*1536 + 1280 + kvh*128;
  float k0v = kb[lane], k1v = kb[lane+64];
  float v0v = vb[lane], v1v = vb[lane+64];
  float mn = wminr(fminf(k0v,k1v));
  float mx = wmaxr(fmaxf(k0v,k1v));
  float sc = fmaxf(mx-mn,1e-5f)/15.0f;
  float inv = 1.0f/sc;
  float bs = fminf(fmaxf(rintf(-mn*inv),0.f),15.f);
  float kq0 = fakeq(k0v,sc,inv,bs), kq1 = fakeq(k1v,sc,inv,bs);
  float c = ct[s*64+lane], sn = st[s*64+lane];
  kb[lane]    = kq0*c - kq1*sn;
  kb[lane+64] = kq1*c + kq0*sn;
  mn = wminr(fminf(v0v,v1v));
  mx = wmaxr(fmaxf(v0v,v1v));
  sc = fmaxf(mx-mn,1e-5f)/15.0f;
  inv = 1.0f/sc;
  bs = fminf(fmaxf(rintf(-mn*inv),0.f),15.f);
  vb[lane]    = fakeq(v0v,sc,inv,bs);
  vb[lane+64] = fakeq(v1v,sc,inv,bs);
}

// ---------------- causal softmax over scores rows (in-place) ----------------
__global__ __launch_bounds__(256) void k_softmax(float* sc){
  int row = blockIdx.x;                 // 16384 = 16*1024
  int i = row & 1023;                   // query position
  float* p = sc + (size_t)row*1024;
  int tid = threadIdx.x, lane = tid & 63, wv = tid >> 6;
  float v[4];
  float m = -3.0e38f;
  #pragma unroll
  for (int k2=0;k2<4;k2++){
    int j = tid + k2*256;
    v[k2] = p[j];
    if (j <= i) m = fmaxf(m, v[k2]);
  }
  __shared__ float red[4];
  m = wmaxr(m);
  if (lane==0) red[wv] = m;
  __syncthreads();
  m = fmaxf(fmaxf(red[0],red[1]), fmaxf(red[2],red[3]));
  float ls = 0.f;
  #pragma unroll
  for (int k2=0;k2<4;k2++){
    int j = tid + k2*256;
    float e = (j <= i) ? __expf(v[k2]-m) : 0.0f;
    v[k2] = e; ls += e;
  }
  __syncthreads();
  ls = wsum(ls);
  if (lane==0) red[wv] = ls;
  __syncthreads();
  float inv = 1.0f / (red[0]+red[1]+red[2]+red[3]);
  #pragma unroll
  for (int k2=0;k2<4;k2++){
    int j = tid + k2*256;
    p[j] = v[k2]*inv;
  }
}

// ---------------- router: logits, softmax, stable top-2, scatter ----------------
__global__ __launch_bounds__(256) void k_router(const float* __restrict__ hn,
                                                const float* __restrict__ wg,
                                                int* cnt, int* toksl, float* wts){
  int t = blockIdx.x*4 + (threadIdx.x>>6);
  int lane = threadIdx.x & 63;
  const float* x = hn + (size_t)t*1024;
  float p[8];
  #pragma unroll
  for (int e=0;e<8;e++) p[e]=0.f;
  for (int i=0;i<16;i++){
    float xv = x[lane + i*64];
    #pragma unroll
    for (int e=0;e<8;e++) p[e] += xv * wg[e*1024 + lane + i*64];
  }
  #pragma unroll
  for (int e=0;e<8;e++) p[e] = wsum(p[e]);
  if (lane==0){
    float m = p[0];
    for (int e=1;e<8;e++) m = fmaxf(m,p[e]);
    float ex[8], sum=0.f;
    for (int e=0;e<8;e++){ ex[e]=__expf(p[e]-m); sum+=ex[e]; }
    float pr[8];
    for (int e=0;e<8;e++) pr[e]=ex[e]/sum;
    int i1 = 0;
    for (int e=1;e<8;e++) if (pr[e] > pr[i1]) i1 = e;   // ties -> lowest idx (stable)
    int i2 = -1;
    for (int e=0;e<8;e++){ if (e==i1) continue; if (i2<0 || pr[e] > pr[i2]) i2 = e; }
    float ssum = pr[i1]+pr[i2];
    float wa = pr[i1]/ssum, wb = pr[i2]/ssum;
    int pos = atomicAdd(cnt+i1,1);
    toksl[i1*2048+pos] = t;          wts[i1*2048+pos] = wa;
    pos = atomicAdd(cnt+i2,1);
    toksl[i2*2048+pos] = t | 65536;  wts[i2*2048+pos] = wb;
  }
}

// ---------------- MoE GEMM1 v2: up = silu(hn@w1^T) * (hn@w3^T) ----------------
// tile 128(tokens) x 128(ffn) dual-B, K=1024, BK=32, double-buffered LDS.
// grid: x = n-tile (padded to 32 for XCD clustering), y = m-tile (16), z = expert-local (4)
__global__ __launch_bounds__(256) void k_moe_gemm1(
    const bf16* __restrict__ hnb, const bf16* __restrict__ w1q, const bf16* __restrict__ w3q,
    const int* __restrict__ cnt, const int* __restrict__ toksl,
    bf16* __restrict__ up, int ebase)
{
  int n0 = blockIdx.x * 128;
  if (n0 >= 3584) return;                       // x padded 28->32
  int el = blockIdx.z, e = ebase + el;
  int c = cnt[e];
  int m0 = blockIdx.y * 128;
  if (m0 >= c) return;
  __shared__ bf16 As[2][128*40];
  __shared__ bf16 B1s[2][128*40];
  __shared__ bf16 B3s[2][128*40];
  int tid = threadIdx.x, lane = tid & 63, wv = tid >> 6;
  int arow = tid >> 1, acol = (tid & 1) * 16;   // each thread: 1 row, 16 K-elems (2x short8)
  int slot = m0 + arow;
  int tok = (slot < c) ? (toksl[e*2048 + slot] & 0xFFFF) : 0;
  const bf16* ap  = hnb + (size_t)tok*1024 + acol;
  const bf16* b1p = w1q + ((size_t)e*3584 + n0 + arow)*1024 + acol;
  const bf16* b3p = w3q + ((size_t)e*3584 + n0 + arow)*1024 + acol;
  int mq = wv & 1, nq = wv >> 1;                // wave sub-tile: 64x64
  int fr = lane & 15, fq = lane >> 4;
  f32x4 zero = {0.f,0.f,0.f,0.f};
  f32x4 acc1[4][4], acc3[4][4];
  #pragma unroll
  for (int i=0;i<4;i++){
    #pragma unroll
    for (int j=0;j<4;j++){ acc1[i][j]=zero; acc3[i][j]=zero; }
  }
  // prologue: stage k=0 into buf 0
  short8 a0 = *(const short8*)(ap);
  short8 a1 = *(const short8*)(ap + 8);
  short8 p0 = *(const short8*)(b1p);
  short8 p1 = *(const short8*)(b1p + 8);
  short8 q0 = *(const short8*)(b3p);
  short8 q1 = *(const short8*)(b3p + 8);
  *(short8*)&As[0][arow*40 + acol]      = a0;
  *(short8*)&As[0][arow*40 + acol + 8]  = a1;
  *(short8*)&B1s[0][arow*40 + acol]     = p0;
  *(short8*)&B1s[0][arow*40 + acol + 8] = p1;
  *(short8*)&B3s[0][arow*40 + acol]     = q0;
  *(short8*)&B3s[0][arow*40 + acol + 8] = q1;
  int buf = 0;
  for (int k0 = 0; k0 < 1024; k0 += 32) {
    __syncthreads();
    bool more = (k0 + 32) < 1024;
    if (more) {
      a0 = *(const short8*)(ap + k0 + 32);
      a1 = *(const short8*)(ap + k0 + 40);
      p0 = *(const short8*)(b1p + k0 + 32);
      p1 = *(const short8*)(b1p + k0 + 40);
      q0 = *(const short8*)(b3p + k0 + 32);
      q1 = *(const short8*)(b3p + k0 + 40);
    }
    short8 aF[4];
    #pragma unroll
    for (int mt=0; mt<4; mt++)
      aF[mt] = *(const short8*)&As[buf][(mq*64 + mt*16 + fr)*40 + fq*8];
    #pragma unroll
    for (int nt=0; nt<4; nt++){
      short8 b1F = *(const short8*)&B1s[buf][(nq*64 + nt*16 + fr)*40 + fq*8];
      short8 b3F = *(const short8*)&B3s[buf][(nq*64 + nt*16 + fr)*40 + fq*8];
      #pragma unroll
      for (int mt=0; mt<4; mt++){
        acc1[mt][nt] = __builtin_amdgcn_mfma_f32_16x16x32_bf16(aF[mt], b1F, acc1[mt][nt], 0,0,0);
        acc3[mt][nt] = __builtin_amdgcn_mfma_f32_16x16x32_bf16(aF[mt], b3F, acc3[mt][nt], 0,0,0);
      }
    }
    if (more) {
      __syncthreads();
      int nb = buf ^ 1;
      *(short8*)&As[nb][arow*40 + acol]      = a0;
      *(short8*)&As[nb][arow*40 + acol + 8]  = a1;
      *(short8*)&B1s[nb][arow*40 + acol]     = p0;
      *(short8*)&B1s[nb][arow*40 + acol + 8] = p1;
      *(short8*)&B3s[nb][arow*40 + acol]     = q0;
      *(short8*)&B3s[nb][arow*40 + acol + 8] = q1;
      buf = nb;
    }
  }
  bf16* upb = up + (size_t)el*2048*3584;
  #pragma unroll
  for (int mt=0; mt<4; mt++){
    #pragma unroll
    for (int nt=0; nt<4; nt++){
      #pragma unroll
      for (int r=0; r<4; r++){
        int srow = m0 + mq*64 + mt*16 + fq*4 + r;   // C layout: row=(lane>>4)*4+reg
        int fcol = n0 + nq*64 + nt*16 + fr;         //           col=lane&15
        float x1 = acc1[mt][nt][r], x3 = acc3[mt][nt][r];
        float u = (x1 / (1.0f + __expf(-x1))) * x3;
        upb[(size_t)srow*3584 + fcol] = __float2bfloat16(u);
      }
    }
  }
}

// ---------------- MoE GEMM2 v2: moe = wt * (up @ w2^T) ----------------
// tile 128 x 128, K=3584, BK=32, double-buffered. grid: x=n(8), y=m(16), z=e(4)
__global__ __launch_bounds__(256) void k_moe_gemm2(
    const bf16* __restrict__ up, const bf16* __restrict__ w2q,
    const int* __restrict__ cnt, const int* __restrict__ toksl,
    const float* __restrict__ wts,
    float* __restrict__ moeA, float* __restrict__ moeB, int ebase)
{
  int el = blockIdx.z, e = ebase + el;
  int c = cnt[e];
  int m0 = blockIdx.y * 128;
  if (m0 >= c) return;
  int n0 = blockIdx.x * 128;
  __shared__ bf16 As[2][128*40];
  __shared__ bf16 Bs[2][128*40];
  int tid = threadIdx.x, lane = tid & 63, wv = tid >> 6;
  int arow = tid >> 1, acol = (tid & 1) * 16;
  const bf16* ap = up + (size_t)el*2048*3584 + (size_t)(m0 + arow)*3584 + acol;
  const bf16* bp = w2q + ((size_t)e*1024 + n0 + arow)*3584 + acol;
  int mq = wv & 1, nq = wv >> 1;
  int fr = lane & 15, fq = lane >> 4;
  f32x4 zero = {0.f,0.f,0.f,0.f};
  f32x4 acc[4][4];
  #pragma unroll
  for (int i=0;i<4;i++){
    #pragma unroll
    for (int j=0;j<4;j++) acc[i][j]=zero;
  }
  short8 a0 = *(const short8*)(ap);
  short8 a1 = *(const short8*)(ap + 8);
  short8 b0 = *(const short8*)(bp);
  short8 b1 = *(const short8*)(bp + 8);
  *(short8*)&As[0][arow*40 + acol]     = a0;
  *(short8*)&As[0][arow*40 + acol + 8] = a1;
  *(short8*)&Bs[0][arow*40 + acol]     = b0;
  *(short8*)&Bs[0][arow*40 + acol + 8] = b1;
  int buf = 0;
  for (int k0 = 0; k0 < 3584; k0 += 32) {
    __syncthreads();
    bool more = (k0 + 32) < 3584;
    if (more) {
      a0 = *(const short8*)(ap + k0 + 32);
      a1 = *(const short8*)(ap + k0 + 40);
      b0 = *(const short8*)(bp + k0 + 32);
      b1 = *(const short8*)(bp + k0 + 40);
    }
    short8 aF[4];
    #pragma unroll
    for (int mt=0; mt<4; mt++)
      aF[mt] = *(const short8*)&As[buf][(mq*64 + mt*16 + fr)*40 + fq*8];
    #pragma unroll
    for (int nt=0; nt<4; nt++){
      short8 bF = *(const short8*)&Bs[buf][(nq*64 + nt*16 + fr)*40 + fq*8];
      #pragma unroll
      for (int mt=0; mt<4; mt++)
        acc[mt][nt] = __builtin_amdgcn_mfma_f32_16x16x32_bf16(aF[mt], bF, acc[mt][nt], 0,0,0);
    }
    if (more) {
      __syncthreads();
      int nb = buf ^ 1;
      *(short8*)&As[nb][arow*40 + acol]     = a0;
      *(short8*)&As[nb][arow*40 + acol + 8] = a1;
      *(short8*)&Bs[nb][arow*40 + acol]     = b0;
      *(short8*)&Bs[nb][arow*40 + acol + 8] = b1;
      buf = nb;
    }
  }
  #pragma unroll
  for (int mt=0; mt<4; mt++){
    #pragma unroll
    for (int nt=0; nt<4; nt++){
      #pragma unroll
      for (int r=0; r<4; r++){
        int srow = m0 + mq*64 + mt*16 + fq*4 + r;
        if (srow < c){
          int ts = toksl[e*2048 + srow];
          int tok = ts & 0xFFFF, fl = ts >> 16;
          float wt = wts[e*2048 + srow];
          int d = n0 + nq*64 + nt*16 + fr;
          float* dst = (fl ? moeB : moeA) + (size_t)tok*1024 + d;
          *dst = acc[mt][nt][r] * wt;
        }
      }
    }
  }
}

// ---------------- final: out = h + moeA + moeB ----------------
__global__ __launch_bounds__(256) void k_final(const float* h, const float* ma,
                                               const float* mb, float* out){
  size_t i = (size_t)blockIdx.x*256 + threadIdx.x;
  float4 a = ((const float4*)h)[i];
  float4 b = ((const float4*)ma)[i];
  float4 c = ((const float4*)mb)[i];
  float4 o;
  o.x = a.x+b.x+c.x; o.y = a.y+b.y+c.y; o.z = a.z+b.z+c.z; o.w = a.w+b.w+c.w;
  ((float4*)out)[i] = o;
}

extern "C" void kernel_launch(void* const* d_in, const int* in_sizes, int n_in,
                              void* d_out, int out_size, void* d_ws, size_t ws_size,
                              hipStream_t stream)
{
  (void)in_sizes; (void)n_in; (void)out_size;
  float* out = (float*)d_out;
  if (ws_size < WS_NEED) { k_sentinel<<<1,1,0,stream>>>(out); return; } // ws too small -> absmax ~12345 marker

  const float* hidden = (const float*)d_in[0];
  const float* w_q  = (const float*)d_in[1];
  const float* w_k  = (const float*)d_in[2];
  const float* w_v  = (const float*)d_in[3];
  const float* w_o  = (const float*)d_in[4];
  const float* g1   = (const float*)d_in[5];
  const float* g2   = (const float*)d_in[6];
  const float* wg   = (const float*)d_in[7];
  const float* w1   = (const float*)d_in[8];
  const float* w3   = (const float*)d_in[9];
  const float* w2   = (const float*)d_in[10];
  char* ws = (char*)d_ws;
  float* WQKV = (float*)(ws + OFF_WQKV);
  float* WOD  = (float*)(ws + OFF_WO);
  bf16*  W1Q  = (bf16*)(ws + OFF_W1Q);
  bf16*  W3Q  = (bf16*)(ws + OFF_W3Q);
  bf16*  W2Q  = (bf16*)(ws + OFF_W2Q);
  float* QKV  = (float*)(ws + OFF_QKV);
  float* SC   = (float*)(ws + OFF_SC);
  bf16*  UP   = (bf16*)(ws + OFF_SC);    // aliases SC (scores dead before MoE)
  float* O2b  = (float*)(ws + OFF_O2);
  float* Hb   = (float*)(ws + OFF_H);
  float* XN   = (float*)(ws + OFF_XN);   // xn, later hn (f32)
  bf16*  HNB  = (bf16*)(ws + OFF_HNB);
  float* CT   = (float*)(ws + OFF_COS);
  float* ST   = (float*)(ws + OFF_SIN);
  int*   CNT  = (int*)(ws + OFF_CNT);
  int*   TOK  = (int*)(ws + OFF_TOK);
  float* WTS  = (float*)(ws + OFF_WTS);
  float* MA   = (float*)(ws + OFF_MA);
  float* MB   = (float*)(ws + OFF_MB);

  k_zero<<<1,64,0,stream>>>(CNT);
  k_rms<<<2048,256,0,stream>>>(hidden, g1, XN, (bf16*)nullptr);
  k_dequant_attn<<<5120,256,0,stream>>>(w_q, w_k, w_v, w_o, WQKV, WOD);
  k_dequant_moe<<<172032,256,0,stream>>>(w1, w3, w2, W1Q, W3Q, W2Q);
  k_rope_tab<<<256,256,0,stream>>>(CT, ST);
  k_qkv_gemm<<<dim3(24,16),256,0,stream>>>(XN, WQKV, QKV);
  k_rope_q<<<4096,256,0,stream>>>(QKV, CT, ST);
  k_kv<<<1024,256,0,stream>>>(QKV, CT, ST);
  k_scores<<<dim3(16,8,16),256,0,stream>>>(QKV, SC);
  k_softmax<<<16384,256,0,stream>>>(SC);
  k_pv<<<dim3(2,16,16),256,0,stream>>>(SC, QKV, O2b);
  k_wo<<<dim3(16,16),256,0,stream>>>(O2b, WOD, hidden, Hb);
  k_rms<<<2048,256,0,stream>>>(Hb, g2, XN, HNB);
  k_router<<<512,256,0,stream>>>(XN, wg, CNT, TOK, WTS);
  k_moe_gemm1<<<dim3(32,16,4),256,0,stream>>>(HNB, W1Q, W3Q, CNT, TOK, UP, 0);
  k_moe_gemm2<<<dim3(8,16,4),256,0,stream>>>(UP, W2Q, CNT, TOK, WTS, MA, MB, 0);
  k_moe_gemm1<<<dim3(32,16,4),256,0,stream>>>(HNB, W1Q, W3Q, CNT, TOK, UP, 4);
  k_moe_gemm2<<<dim3(8,16,4),256,0,stream>>>(UP, W2Q, CNT, TOK, WTS, MA, MB, 4);
  k_final<<<2048,256,0,stream>>>(Hb, MA, MB, out);
}

// Round 5
// 1219.889 us; speedup vs baseline: 1.1905x; 1.0324x over previous
//
#include <hip/hip_runtime.h>
#include <hip/hip_bf16.h>

// QMixtralDecoderLayer: B=2 S=1024 D=1024 H=8 KVH=2 HD=128 E=8 TOPK=2 FFN=3584
// int4 group fake-quant (GS=128), RoPE theta=1e6, RMS eps=1e-5.
// Strategy: attention path f32 (router stability), MoE in bf16 MFMA.
// R2: MoE GEMMs -> 128x128 tiles, double-buffered LDS, n-major grid.
// R3: dequant: hoist divisions (1/s once per group).
// R4: dequant: group = 32 lanes x float4 (width-32 DPP reduction, no wave64 bpermute chain).

typedef __attribute__((ext_vector_type(4))) float f32x4;
typedef __attribute__((ext_vector_type(8))) short short8;
typedef __hip_bfloat16 bf16;

#define DEV static __device__ __forceinline__

DEV float wsum(float v){
  #pragma unroll
  for (int o=32;o>0;o>>=1) v += __shfl_xor(v,o,64);
  return v;
}
DEV float wmaxr(float v){
  #pragma unroll
  for (int o=32;o>0;o>>=1) v = fmaxf(v,__shfl_xor(v,o,64));
  return v;
}
DEV float wminr(float v){
  #pragma unroll
  for (int o=32;o>0;o>>=1) v = fminf(v,__shfl_xor(v,o,64));
  return v;
}
// 32-lane (half-wave) reductions: masks <=16 -> DPP/swizzle, no cross-32 bpermute
DEV float wmax32(float v){
  #pragma unroll
  for (int o=16;o>0;o>>=1) v = fmaxf(v,__shfl_xor(v,o,32));
  return v;
}
DEV float wmin32(float v){
  #pragma unroll
  for (int o=16;o>0;o>>=1) v = fminf(v,__shfl_xor(v,o,32));
  return v;
}
// matches: (clip(round(x/s)+b,0,15)-b)*s with round-half-even; inv = 1/s hoisted
DEV float fakeq(float x, float s, float inv, float b){
  return (fminf(fmaxf(rintf(x*inv)+b,0.f),15.f)-b)*s;
}

// ---------------- workspace layout (bytes) ----------------
constexpr size_t OFF_WQKV = 0;                         // 1536*1024 f32 (dequant wq|wk|wv)
constexpr size_t OFF_WO   = OFF_WQKV + 6291456;        // 1024*1024 f32
constexpr size_t OFF_W1Q  = OFF_WO   + 4194304;        // 8*3584*1024 bf16
constexpr size_t OFF_W3Q  = OFF_W1Q  + 58720256;
constexpr size_t OFF_W2Q  = OFF_W3Q  + 58720256;
constexpr size_t OFF_QKV  = OFF_W2Q  + 58720256;       // 2048*1536 f32
constexpr size_t OFF_SC   = OFF_QKV  + 12582912;       // 16*1024*1024 f32; later UP 4*2048*3584 bf16
constexpr size_t OFF_O2   = OFF_SC   + 67108864;       // 2048*1024 f32
constexpr size_t OFF_H    = OFF_O2   + 8388608;        // 2048*1024 f32
constexpr size_t OFF_XN   = OFF_H    + 8388608;        // xn then hn (f32)
constexpr size_t OFF_HNB  = OFF_XN   + 8388608;        // hn bf16
constexpr size_t OFF_COS  = OFF_HNB  + 4194304;        // 1024*64 f32
constexpr size_t OFF_SIN  = OFF_COS  + 262144;
constexpr size_t OFF_CNT  = OFF_SIN  + 262144;         // 8 ints (+pad)
constexpr size_t OFF_TOK  = OFF_CNT  + 256;            // 8*2048 int
constexpr size_t OFF_WTS  = OFF_TOK  + 65536;          // 8*2048 f32
constexpr size_t OFF_MA   = OFF_WTS  + 65536;          // 2048*1024 f32
constexpr size_t OFF_MB   = OFF_MA   + 8388608;
constexpr size_t WS_NEED  = OFF_MB   + 8388608;        // ~299 MB

__global__ void k_sentinel(float* out){ out[0] = 12345.0f; }
__global__ void k_zero(int* cnt){ if (threadIdx.x < 8) cnt[threadIdx.x] = 0; }

// ---------------- RMSNorm (f32 in, f32 out + optional bf16 out) ----------------
__global__ __launch_bounds__(256) void k_rms(const float* __restrict__ x,
                                             const float* __restrict__ g,
                                             float* __restrict__ out,
                                             bf16* __restrict__ outb)
{
  int row = blockIdx.x, tid = threadIdx.x;
  const float4* x4 = (const float4*)(x + (size_t)row*1024);
  float4 v = x4[tid];
  float ss = v.x*v.x + v.y*v.y + v.z*v.z + v.w*v.w;
  int lane = tid & 63, wv = tid >> 6;
  ss = wsum(ss);
  __shared__ float red[4];
  if (lane == 0) red[wv] = ss;
  __syncthreads();
  float tot = red[0]+red[1]+red[2]+red[3];
  float r = 1.0f / sqrtf(tot * (1.0f/1024.0f) + 1e-5f);
  float4 gg = ((const float4*)g)[tid];
  float4 o;
  o.x = v.x*r*gg.x; o.y = v.y*r*gg.y; o.z = v.z*r*gg.z; o.w = v.w*r*gg.w;
  ((float4*)(out + (size_t)row*1024))[tid] = o;
  if (outb) {
    bf16* ob = outb + (size_t)row*1024 + tid*4;
    ob[0]=__float2bfloat16(o.x); ob[1]=__float2bfloat16(o.y);
    ob[2]=__float2bfloat16(o.z); ob[3]=__float2bfloat16(o.w);
  }
}

// ---------------- weight dequant: attention (f32 out) ----------------
// group = 32 lanes x float4; 8 groups per 256-block; 20480 groups total
__global__ __launch_bounds__(256) void k_dequant_attn(
    const float* __restrict__ wq, const float* __restrict__ wk,
    const float* __restrict__ wv, const float* __restrict__ wo,
    float* __restrict__ wqkv, float* __restrict__ wod)
{
  int g = blockIdx.x*8 + (threadIdx.x>>5);
  int l = threadIdx.x & 31;
  const float* src; float* dst;
  if (g < 8192)       { size_t o=(size_t)g*128;          src = wq + o; dst = wqkv + o; }
  else if (g < 10240) { size_t o=(size_t)(g-8192)*128;   src = wk + o; dst = wqkv + (size_t)1024*1024 + o; }
  else if (g < 12288) { size_t o=(size_t)(g-10240)*128;  src = wv + o; dst = wqkv + (size_t)1280*1024 + o; }
  else                { size_t o=(size_t)(g-12288)*128;  src = wo + o; dst = wod + o; }
  float4 x = *(const float4*)(src + l*4);
  float mn = wmin32(fminf(fminf(x.x,x.y), fminf(x.z,x.w)));
  float mx = wmax32(fmaxf(fmaxf(x.x,x.y), fmaxf(x.z,x.w)));
  float s = fmaxf(mx-mn, 1e-5f) / 15.0f;
  float inv = 1.0f / s;
  float b = fminf(fmaxf(rintf(-mn*inv),0.f),15.f);
  float4 o4;
  o4.x = fakeq(x.x,s,inv,b); o4.y = fakeq(x.y,s,inv,b);
  o4.z = fakeq(x.z,s,inv,b); o4.w = fakeq(x.w,s,inv,b);
  *(float4*)(dst + l*4) = o4;
}

// ---------------- weight dequant: MoE (bf16 out) ----------------
// group = 32 lanes x float4; block covers 1024 contiguous elems (8 groups)
__global__ __launch_bounds__(256) void k_dequant_moe(
    const float* __restrict__ w1, const float* __restrict__ w3,
    const float* __restrict__ w2,
    bf16* __restrict__ o1, bf16* __restrict__ o3, bf16* __restrict__ o2q)
{
  int b = blockIdx.x;                 // 0..86015
  const int BPT = 28672;              // blocks per tensor (29360128 elems / 1024)
  const float* src; bf16* dst;
  if (b < BPT)        { src = w1; dst = o1; }
  else if (b < 2*BPT) { src = w3; dst = o3;  b -= BPT; }
  else                { src = w2; dst = o2q; b -= 2*BPT; }
  size_t off = (size_t)b*1024 + threadIdx.x*4;
  float4 x = *(const float4*)(src + off);
  float mn = wmin32(fminf(fminf(x.x,x.y), fminf(x.z,x.w)));
  float mx = wmax32(fmaxf(fmaxf(x.x,x.y), fmaxf(x.z,x.w)));
  float s = fmaxf(mx-mn, 1e-5f) / 15.0f;
  float inv = 1.0f / s;
  float bse = fminf(fmaxf(rintf(-mn*inv),0.f),15.f);
  union { ushort4 u; bf16 h[4]; } pk;
  pk.h[0] = __float2bfloat16(fakeq(x.x,s,inv,bse));
  pk.h[1] = __float2bfloat16(fakeq(x.y,s,inv,bse));
  pk.h[2] = __float2bfloat16(fakeq(x.z,s,inv,bse));
  pk.h[3] = __float2bfloat16(fakeq(x.w,s,inv,bse));
  *(ushort4*)(dst + off) = pk.u;
}

// ---------------- RoPE tables ----------------
__global__ __launch_bounds__(256) void k_rope_tab(float* ct, float* st)
{
  int s = blockIdx.x*4 + (threadIdx.x>>6);
  int l = threadIdx.x & 63;
  float inv = 1.0f / powf(1.0e6f, (float)l * (1.0f/64.0f));
  float f = (float)s * inv;
  ct[s*64 + l] = cosf(f);
  st[s*64 + l] = sinf(f);
}

// ---------------- f32 GEMM core: C[M,N] = A[M,K] * B[N,K]^T (tile 128x64) ----------------
DEV void gemm_bt_128x64(const float* __restrict__ A, int lda,
                        const float* __restrict__ Bm, int ldb,
                        float* __restrict__ C, int ldc,
                        const float* __restrict__ resid,
                        int K, float scale, int m0, int n0)
{
  __shared__ float As[16*136];
  __shared__ float Bs[16*72];
  int tid = threadIdx.x;
  int ar = tid >> 1, ak = (tid & 1) * 8;
  int br = tid >> 2, bk = (tid & 3) * 4;
  const float* ap = A + (size_t)(m0 + ar)*lda + ak;
  const float* bp = Bm + (size_t)(n0 + br)*ldb + bk;
  int ty = tid >> 4, tx = tid & 15;
  int r0 = ty*8, c0 = tx*4;
  float acc[8][4];
  #pragma unroll
  for (int i=0;i<8;i++){
    #pragma unroll
    for (int j=0;j<4;j++) acc[i][j]=0.f;
  }
  for (int k0 = 0; k0 < K; k0 += 16) {
    float4 a0 = *(const float4*)(ap + k0);
    float4 a1 = *(const float4*)(ap + k0 + 4);
    float4 b0 = *(const float4*)(bp + k0);
    __syncthreads();
    As[(ak+0)*136+ar]=a0.x; As[(ak+1)*136+ar]=a0.y; As[(ak+2)*136+ar]=a0.z; As[(ak+3)*136+ar]=a0.w;
    As[(ak+4)*136+ar]=a1.x; As[(ak+5)*136+ar]=a1.y; As[(ak+6)*136+ar]=a1.z; As[(ak+7)*136+ar]=a1.w;
    Bs[(bk+0)*72+br]=b0.x;  Bs[(bk+1)*72+br]=b0.y;  Bs[(bk+2)*72+br]=b0.z;  Bs[(bk+3)*72+br]=b0.w;
    __syncthreads();
    #pragma unroll
    for (int kk = 0; kk < 16; kk++) {
      float4 xa = *(const float4*)&As[kk*136 + r0];
      float4 xb = *(const float4*)&As[kk*136 + r0 + 4];
      float4 yb = *(const float4*)&Bs[kk*72 + c0];
      float xs[8] = {xa.x,xa.y,xa.z,xa.w,xb.x,xb.y,xb.z,xb.w};
      float ys[4] = {yb.x,yb.y,yb.z,yb.w};
      #pragma unroll
      for (int i=0;i<8;i++){
        #pragma unroll
        for (int j=0;j<4;j++) acc[i][j] += xs[i]*ys[j];
      }
    }
  }
  #pragma unroll
  for (int i=0;i<8;i++){
    size_t ro = (size_t)(m0 + r0 + i)*ldc + n0 + c0;
    #pragma unroll
    for (int j=0;j<4;j++){
      float v = acc[i][j]*scale;
      if (resid) v += resid[ro + j];
      C[ro + j] = v;
    }
  }
}

__global__ __launch_bounds__(256) void k_qkv_gemm(const float* xn, const float* wqkv, float* qkv){
  gemm_bt_128x64(xn, 1024, wqkv, 1024, qkv, 1536, nullptr, 1024, 1.0f,
                 blockIdx.y*128, blockIdx.x*64);
}
__global__ __launch_bounds__(256) void k_wo(const float* o2, const float* wod,
                                            const float* hidden, float* h){
  gemm_bt_128x64(o2, 1024, wod, 1024, h, 1024, hidden, 1024, 1.0f,
                 blockIdx.y*128, blockIdx.x*64);
}
__global__ __launch_bounds__(256) void k_scores(const float* qkv, float* sc){
  int z = blockIdx.z, b = z >> 3, h = z & 7;
  int m0 = blockIdx.y*128, n0 = blockIdx.x*64;
  if (n0 > m0 + 127) return;   // fully-masked causal tile
  const float* A  = qkv + (size_t)b*1024*1536 + h*128;
  const float* Bp = qkv + (size_t)b*1024*1536 + 1024 + (h>>2)*128;
  float* C = sc + (size_t)z*1024*1024;
  gemm_bt_128x64(A, 1536, Bp, 1536, C, 1024, nullptr, 128, 0.08838834764831845f, m0, n0);
}

// ---------------- f32 GEMM core: C = A[M,K]*B[K,N] (tile 64x64), for attn@V ----------------
DEV void gemm_nn_64x64(const float* __restrict__ A, int lda,
                       const float* __restrict__ Bm, int ldb,
                       float* __restrict__ C, int ldc,
                       int kmax, int m0, int n0)
{
  __shared__ float As[16*68];
  __shared__ float Bs[16*68];
  int tid = threadIdx.x;
  int ar = tid >> 2, ak = (tid & 3)*4;
  int bk = tid >> 4, bc = (tid & 15)*4;
  const float* ap = A + (size_t)(m0 + ar)*lda + ak;
  const float* bp = Bm + (size_t)bk*ldb + n0 + bc;
  int ty = tid >> 4, tx = tid & 15;
  int r0 = ty*4, c0 = tx*4;
  float acc[4][4];
  #pragma unroll
  for (int i=0;i<4;i++){
    #pragma unroll
    for (int j=0;j<4;j++) acc[i][j]=0.f;
  }
  for (int k0 = 0; k0 < kmax; k0 += 16) {
    float4 a = *(const float4*)(ap + k0);
    float4 b = *(const float4*)(bp + (size_t)k0*ldb);
    __syncthreads();
    As[(ak+0)*68+ar]=a.x; As[(ak+1)*68+ar]=a.y; As[(ak+2)*68+ar]=a.z; As[(ak+3)*68+ar]=a.w;
    *(float4*)&Bs[bk*68 + bc] = b;
    __syncthreads();
    #pragma unroll
    for (int kk = 0; kk < 16; kk++) {
      float4 xa = *(const float4*)&As[kk*68 + r0];
      float4 yb = *(const float4*)&Bs[kk*68 + c0];
      float xs[4] = {xa.x,xa.y,xa.z,xa.w};
      float ys[4] = {yb.x,yb.y,yb.z,yb.w};
      #pragma unroll
      for (int i=0;i<4;i++){
        #pragma unroll
        for (int j=0;j<4;j++) acc[i][j] += xs[i]*ys[j];
      }
    }
  }
  #pragma unroll
  for (int i=0;i<4;i++){
    size_t ro = (size_t)(m0 + r0 + i)*ldc + n0 + c0;
    #pragma unroll
    for (int j=0;j<4;j++) C[ro + j] = acc[i][j];
  }
}

__global__ __launch_bounds__(256) void k_pv(const float* sc, const float* qkv, float* o2){
  int z = blockIdx.z, b = z >> 3, h = z & 7;
  int m0 = blockIdx.y*64, n0 = blockIdx.x*64;
  const float* A  = sc + (size_t)z*1024*1024;
  const float* Bp = qkv + (size_t)b*1024*1536 + 1280 + (h>>2)*128;
  float* C = o2 + (size_t)b*1024*1024 + h*128;
  gemm_nn_64x64(A, 1024, Bp, 1536, C, 1024, m0 + 64 /*causal kmax*/, m0, n0);
}

// ---------------- RoPE q (in-place in qkv) ----------------
__global__ __launch_bounds__(256) void k_rope_q(float* qkv, const float* ct, const float* st){
  int wid = blockIdx.x*4 + (threadIdx.x>>6);   // 0..16383
  int lane = threadIdx.x & 63;
  int t = wid >> 3, h = wid & 7;
  int s = t & 1023;
  float* base = qkv + (size_t)t*1536 + h*128;
  float x0 = base[lane], x1 = base[lane+64];
  float c = ct[s*64+lane], sn = st[s*64+lane];
  base[lane]    = x0*c - x1*sn;
  base[lane+64] = x1*c + x0*sn;
}

// ---------------- k: fake-quant then RoPE; v: fake-quant (in-place) ----------------
__global__ __launch_bounds__(256) void k_kv(float* qkv, const float* ct, const float* st){
  int wid = blockIdx.x*4 + (threadIdx.x>>6);   // 0..4095
  int lane = threadIdx.x & 63;
  int t = wid >> 1, kvh = wid & 1;
  int s = t & 1023;
  float* kb = qkv + (size_t)t*1536 + 1024 + kvh*128;
  float* vb = qkv + (size_t)t*1536 + 1280 + kvh*128;
  float k0v = kb[lane], k1v = kb[lane+64];
  float v0v = vb[lane], v1v = vb[lane+64];
  float mn = wminr(fminf(k0v,k1v));
  float mx = wmaxr(fmaxf(k0v,k1v));
  float sc = fmaxf(mx-mn,1e-5f)/15.0f;
  float inv = 1.0f/sc;
  float bs = fminf(fmaxf(rintf(-mn*inv),0.f),15.f);
  float kq0 = fakeq(k0v,sc,inv,bs), kq1 = fakeq(k1v,sc,inv,bs);
  float c = ct[s*64+lane], sn = st[s*64+lane];
  kb[lane]    = kq0*c - kq1*sn;
  kb[lane+64] = kq1*c + kq0*sn;
  mn = wminr(fminf(v0v,v1v));
  mx = wmaxr(fmaxf(v0v,v1v));
  sc = fmaxf(mx-mn,1e-5f)/15.0f;
  inv = 1.0f/sc;
  bs = fminf(fmaxf(rintf(-mn*inv),0.f),15.f);
  vb[lane]    = fakeq(v0v,sc,inv,bs);
  vb[lane+64] = fakeq(v1v,sc,inv,bs);
}

// ---------------- causal softmax over scores rows (in-place) ----------------
__global__ __launch_bounds__(256) void k_softmax(float* sc){
  int row = blockIdx.x;                 // 16384 = 16*1024
  int i = row & 1023;                   // query position
  float* p = sc + (size_t)row*1024;
  int tid = threadIdx.x, lane = tid & 63, wv = tid >> 6;
  float v[4];
  float m = -3.0e38f;
  #pragma unroll
  for (int k2=0;k2<4;k2++){
    int j = tid + k2*256;
    v[k2] = p[j];
    if (j <= i) m = fmaxf(m, v[k2]);
  }
  __shared__ float red[4];
  m = wmaxr(m);
  if (lane==0) red[wv] = m;
  __syncthreads();
  m = fmaxf(fmaxf(red[0],red[1]), fmaxf(red[2],red[3]));
  float ls = 0.f;
  #pragma unroll
  for (int k2=0;k2<4;k2++){
    int j = tid + k2*256;
    float e = (j <= i) ? __expf(v[k2]-m) : 0.0f;
    v[k2] = e; ls += e;
  }
  __syncthreads();
  ls = wsum(ls);
  if (lane==0) red[wv] = ls;
  __syncthreads();
  float inv = 1.0f / (red[0]+red[1]+red[2]+red[3]);
  #pragma unroll
  for (int k2=0;k2<4;k2++){
    int j = tid + k2*256;
    p[j] = v[k2]*inv;
  }
}

// ---------------- router: logits, softmax, stable top-2, scatter ----------------
__global__ __launch_bounds__(256) void k_router(const float* __restrict__ hn,
                                                const float* __restrict__ wg,
                                                int* cnt, int* toksl, float* wts){
  int t = blockIdx.x*4 + (threadIdx.x>>6);
  int lane = threadIdx.x & 63;
  const float* x = hn + (size_t)t*1024;
  float p[8];
  #pragma unroll
  for (int e=0;e<8;e++) p[e]=0.f;
  for (int i=0;i<16;i++){
    float xv = x[lane + i*64];
    #pragma unroll
    for (int e=0;e<8;e++) p[e] += xv * wg[e*1024 + lane + i*64];
  }
  #pragma unroll
  for (int e=0;e<8;e++) p[e] = wsum(p[e]);
  if (lane==0){
    float m = p[0];
    for (int e=1;e<8;e++) m = fmaxf(m,p[e]);
    float ex[8], sum=0.f;
    for (int e=0;e<8;e++){ ex[e]=__expf(p[e]-m); sum+=ex[e]; }
    float pr[8];
    for (int e=0;e<8;e++) pr[e]=ex[e]/sum;
    int i1 = 0;
    for (int e=1;e<8;e++) if (pr[e] > pr[i1]) i1 = e;   // ties -> lowest idx (stable)
    int i2 = -1;
    for (int e=0;e<8;e++){ if (e==i1) continue; if (i2<0 || pr[e] > pr[i2]) i2 = e; }
    float ssum = pr[i1]+pr[i2];
    float wa = pr[i1]/ssum, wb = pr[i2]/ssum;
    int pos = atomicAdd(cnt+i1,1);
    toksl[i1*2048+pos] = t;          wts[i1*2048+pos] = wa;
    pos = atomicAdd(cnt+i2,1);
    toksl[i2*2048+pos] = t | 65536;  wts[i2*2048+pos] = wb;
  }
}

// ---------------- MoE GEMM1 v2: up = silu(hn@w1^T) * (hn@w3^T) ----------------
// tile 128(tokens) x 128(ffn) dual-B, K=1024, BK=32, double-buffered LDS.
// grid: x = n-tile (padded to 32 for XCD clustering), y = m-tile (16), z = expert-local (4)
__global__ __launch_bounds__(256) void k_moe_gemm1(
    const bf16* __restrict__ hnb, const bf16* __restrict__ w1q, const bf16* __restrict__ w3q,
    const int* __restrict__ cnt, const int* __restrict__ toksl,
    bf16* __restrict__ up, int ebase)
{
  int n0 = blockIdx.x * 128;
  if (n0 >= 3584) return;                       // x padded 28->32
  int el = blockIdx.z, e = ebase + el;
  int c = cnt[e];
  int m0 = blockIdx.y * 128;
  if (m0 >= c) return;
  __shared__ bf16 As[2][128*40];
  __shared__ bf16 B1s[2][128*40];
  __shared__ bf16 B3s[2][128*40];
  int tid = threadIdx.x, lane = tid & 63, wv = tid >> 6;
  int arow = tid >> 1, acol = (tid & 1) * 16;   // each thread: 1 row, 16 K-elems (2x short8)
  int slot = m0 + arow;
  int tok = (slot < c) ? (toksl[e*2048 + slot] & 0xFFFF) : 0;
  const bf16* ap  = hnb + (size_t)tok*1024 + acol;
  const bf16* b1p = w1q + ((size_t)e*3584 + n0 + arow)*1024 + acol;
  const bf16* b3p = w3q + ((size_t)e*3584 + n0 + arow)*1024 + acol;
  int mq = wv & 1, nq = wv >> 1;                // wave sub-tile: 64x64
  int fr = lane & 15, fq = lane >> 4;
  f32x4 zero = {0.f,0.f,0.f,0.f};
  f32x4 acc1[4][4], acc3[4][4];
  #pragma unroll
  for (int i=0;i<4;i++){
    #pragma unroll
    for (int j=0;j<4;j++){ acc1[i][j]=zero; acc3[i][j]=zero; }
  }
  // prologue: stage k=0 into buf 0
  short8 a0 = *(const short8*)(ap);
  short8 a1 = *(const short8*)(ap + 8);
  short8 p0 = *(const short8*)(b1p);
  short8 p1 = *(const short8*)(b1p + 8);
  short8 q0 = *(const short8*)(b3p);
  short8 q1 = *(const short8*)(b3p + 8);
  *(short8*)&As[0][arow*40 + acol]      = a0;
  *(short8*)&As[0][arow*40 + acol + 8]  = a1;
  *(short8*)&B1s[0][arow*40 + acol]     = p0;
  *(short8*)&B1s[0][arow*40 + acol + 8] = p1;
  *(short8*)&B3s[0][arow*40 + acol]     = q0;
  *(short8*)&B3s[0][arow*40 + acol + 8] = q1;
  int buf = 0;
  for (int k0 = 0; k0 < 1024; k0 += 32) {
    __syncthreads();
    bool more = (k0 + 32) < 1024;
    if (more) {
      a0 = *(const short8*)(ap + k0 + 32);
      a1 = *(const short8*)(ap + k0 + 40);
      p0 = *(const short8*)(b1p + k0 + 32);
      p1 = *(const short8*)(b1p + k0 + 40);
      q0 = *(const short8*)(b3p + k0 + 32);
      q1 = *(const short8*)(b3p + k0 + 40);
    }
    short8 aF[4];
    #pragma unroll
    for (int mt=0; mt<4; mt++)
      aF[mt] = *(const short8*)&As[buf][(mq*64 + mt*16 + fr)*40 + fq*8];
    #pragma unroll
    for (int nt=0; nt<4; nt++){
      short8 b1F = *(const short8*)&B1s[buf][(nq*64 + nt*16 + fr)*40 + fq*8];
      short8 b3F = *(const short8*)&B3s[buf][(nq*64 + nt*16 + fr)*40 + fq*8];
      #pragma unroll
      for (int mt=0; mt<4; mt++){
        acc1[mt][nt] = __builtin_amdgcn_mfma_f32_16x16x32_bf16(aF[mt], b1F, acc1[mt][nt], 0,0,0);
        acc3[mt][nt] = __builtin_amdgcn_mfma_f32_16x16x32_bf16(aF[mt], b3F, acc3[mt][nt], 0,0,0);
      }
    }
    if (more) {
      __syncthreads();
      int nb = buf ^ 1;
      *(short8*)&As[nb][arow*40 + acol]      = a0;
      *(short8*)&As[nb][arow*40 + acol + 8]  = a1;
      *(short8*)&B1s[nb][arow*40 + acol]     = p0;
      *(short8*)&B1s[nb][arow*40 + acol + 8] = p1;
      *(short8*)&B3s[nb][arow*40 + acol]     = q0;
      *(short8*)&B3s[nb][arow*40 + acol + 8] = q1;
      buf = nb;
    }
  }
  bf16* upb = up + (size_t)el*2048*3584;
  #pragma unroll
  for (int mt=0; mt<4; mt++){
    #pragma unroll
    for (int nt=0; nt<4; nt++){
      #pragma unroll
      for (int r=0; r<4; r++){
        int srow = m0 + mq*64 + mt*16 + fq*4 + r;   // C layout: row=(lane>>4)*4+reg
        int fcol = n0 + nq*64 + nt*16 + fr;         //           col=lane&15
        float x1 = acc1[mt][nt][r], x3 = acc3[mt][nt][r];
        float u = (x1 / (1.0f + __expf(-x1))) * x3;
        upb[(size_t)srow*3584 + fcol] = __float2bfloat16(u);
      }
    }
  }
}

// ---------------- MoE GEMM2 v2: moe = wt * (up @ w2^T) ----------------
// tile 128 x 128, K=3584, BK=32, double-buffered. grid: x=n(8), y=m(16), z=e(4)
__global__ __launch_bounds__(256) void k_moe_gemm2(
    const bf16* __restrict__ up, const bf16* __restrict__ w2q,
    const int* __restrict__ cnt, const int* __restrict__ toksl,
    const float* __restrict__ wts,
    float* __restrict__ moeA, float* __restrict__ moeB, int ebase)
{
  int el = blockIdx.z, e = ebase + el;
  int c = cnt[e];
  int m0 = blockIdx.y * 128;
  if (m0 >= c) return;
  int n0 = blockIdx.x * 128;
  __shared__ bf16 As[2][128*40];
  __shared__ bf16 Bs[2][128*40];
  int tid = threadIdx.x, lane = tid & 63, wv = tid >> 6;
  int arow = tid >> 1, acol = (tid & 1) * 16;
  const bf16* ap = up + (size_t)el*2048*3584 + (size_t)(m0 + arow)*3584 + acol;
  const bf16* bp = w2q + ((size_t)e*1024 + n0 + arow)*3584 + acol;
  int mq = wv & 1, nq = wv >> 1;
  int fr = lane & 15, fq = lane >> 4;
  f32x4 zero = {0.f,0.f,0.f,0.f};
  f32x4 acc[4][4];
  #pragma unroll
  for (int i=0;i<4;i++){
    #pragma unroll
    for (int j=0;j<4;j++) acc[i][j]=zero;
  }
  short8 a0 = *(const short8*)(ap);
  short8 a1 = *(const short8*)(ap + 8);
  short8 b0 = *(const short8*)(bp);
  short8 b1 = *(const short8*)(bp + 8);
  *(short8*)&As[0][arow*40 + acol]     = a0;
  *(short8*)&As[0][arow*40 + acol + 8] = a1;
  *(short8*)&Bs[0][arow*40 + acol]     = b0;
  *(short8*)&Bs[0][arow*40 + acol + 8] = b1;
  int buf = 0;
  for (int k0 = 0; k0 < 3584; k0 += 32) {
    __syncthreads();
    bool more = (k0 + 32) < 3584;
    if (more) {
      a0 = *(const short8*)(ap + k0 + 32);
      a1 = *(const short8*)(ap + k0 + 40);
      b0 = *(const short8*)(bp + k0 + 32);
      b1 = *(const short8*)(bp + k0 + 40);
    }
    short8 aF[4];
    #pragma unroll
    for (int mt=0; mt<4; mt++)
      aF[mt] = *(const short8*)&As[buf][(mq*64 + mt*16 + fr)*40 + fq*8];
    #pragma unroll
    for (int nt=0; nt<4; nt++){
      short8 bF = *(const short8*)&Bs[buf][(nq*64 + nt*16 + fr)*40 + fq*8];
      #pragma unroll
      for (int mt=0; mt<4; mt++)
        acc[mt][nt] = __builtin_amdgcn_mfma_f32_16x16x32_bf16(aF[mt], bF, acc[mt][nt], 0,0,0);
    }
    if (more) {
      __syncthreads();
      int nb = buf ^ 1;
      *(short8*)&As[nb][arow*40 + acol]     = a0;
      *(short8*)&As[nb][arow*40 + acol + 8] = a1;
      *(short8*)&Bs[nb][arow*40 + acol]     = b0;
      *(short8*)&Bs[nb][arow*40 + acol + 8] = b1;
      buf = nb;
    }
  }
  #pragma unroll
  for (int mt=0; mt<4; mt++){
    #pragma unroll
    for (int nt=0; nt<4; nt++){
      #pragma unroll
      for (int r=0; r<4; r++){
        int srow = m0 + mq*64 + mt*16 + fq*4 + r;
        if (srow < c){
          int ts = toksl[e*2048 + srow];
          int tok = ts & 0xFFFF, fl = ts >> 16;
          float wt = wts[e*2048 + srow];
          int d = n0 + nq*64 + nt*16 + fr;
          float* dst = (fl ? moeB : moeA) + (size_t)tok*1024 + d;
          *dst = acc[mt][nt][r] * wt;
        }
      }
    }
  }
}

// ---------------- final: out = h + moeA + moeB ----------------
__global__ __launch_bounds__(256) void k_final(const float* h, const float* ma,
                                               const float* mb, float* out){
  size_t i = (size_t)blockIdx.x*256 + threadIdx.x;
  float4 a = ((const float4*)h)[i];
  float4 b = ((const float4*)ma)[i];
  float4 c = ((const float4*)mb)[i];
  float4 o;
  o.x = a.x+b.x+c.x; o.y = a.y+b.y+c.y; o.z = a.z+b.z+c.z; o.w = a.w+b.w+c.w;
  ((float4*)out)[i] = o;
}

extern "C" void kernel_launch(void* const* d_in, const int* in_sizes, int n_in,
                              void* d_out, int out_size, void* d_ws, size_t ws_size,
                              hipStream_t stream)
{
  (void)in_sizes; (void)n_in; (void)out_size;
  float* out = (float*)d_out;
  if (ws_size < WS_NEED) { k_sentinel<<<1,1,0,stream>>>(out); return; } // ws too small -> absmax ~12345 marker

  const float* hidden = (const float*)d_in[0];
  const float* w_q  = (const float*)d_in[1];
  const float* w_k  = (const float*)d_in[2];
  const float* w_v  = (const float*)d_in[3];
  const float* w_o  = (const float*)d_in[4];
  const float* g1   = (const float*)d_in[5];
  const float* g2   = (const float*)d_in[6];
  const float* wg   = (const float*)d_in[7];
  const float* w1   = (const float*)d_in[8];
  const float* w3   = (const float*)d_in[9];
  const float* w2   = (const float*)d_in[10];
  char* ws = (char*)d_ws;
  float* WQKV = (float*)(ws + OFF_WQKV);
  float* WOD  = (float*)(ws + OFF_WO);
  bf16*  W1Q  = (bf16*)(ws + OFF_W1Q);
  bf16*  W3Q  = (bf16*)(ws + OFF_W3Q);
  bf16*  W2Q  = (bf16*)(ws + OFF_W2Q);
  float* QKV  = (float*)(ws + OFF_QKV);
  float* SC   = (float*)(ws + OFF_SC);
  bf16*  UP   = (bf16*)(ws + OFF_SC);    // aliases SC (scores dead before MoE)
  float* O2b  = (float*)(ws + OFF_O2);
  float* Hb   = (float*)(ws + OFF_H);
  float* XN   = (float*)(ws + OFF_XN);   // xn, later hn (f32)
  bf16*  HNB  = (bf16*)(ws + OFF_HNB);
  float* CT   = (float*)(ws + OFF_COS);
  float* ST   = (float*)(ws + OFF_SIN);
  int*   CNT  = (int*)(ws + OFF_CNT);
  int*   TOK  = (int*)(ws + OFF_TOK);
  float* WTS  = (float*)(ws + OFF_WTS);
  float* MA   = (float*)(ws + OFF_MA);
  float* MB   = (float*)(ws + OFF_MB);

  k_zero<<<1,64,0,stream>>>(CNT);
  k_rms<<<2048,256,0,stream>>>(hidden, g1, XN, (bf16*)nullptr);
  k_dequant_attn<<<2560,256,0,stream>>>(w_q, w_k, w_v, w_o, WQKV, WOD);
  k_dequant_moe<<<86016,256,0,stream>>>(w1, w3, w2, W1Q, W3Q, W2Q);
  k_rope_tab<<<256,256,0,stream>>>(CT, ST);
  k_qkv_gemm<<<dim3(24,16),256,0,stream>>>(XN, WQKV, QKV);
  k_rope_q<<<4096,256,0,stream>>>(QKV, CT, ST);
  k_kv<<<1024,256,0,stream>>>(QKV, CT, ST);
  k_scores<<<dim3(16,8,16),256,0,stream>>>(QKV, SC);
  k_softmax<<<16384,256,0,stream>>>(SC);
  k_pv<<<dim3(2,16,16),256,0,stream>>>(SC, QKV, O2b);
  k_wo<<<dim3(16,16),256,0,stream>>>(O2b, WOD, hidden, Hb);
  k_rms<<<2048,256,0,stream>>>(Hb, g2, XN, HNB);
  k_router<<<512,256,0,stream>>>(XN, wg, CNT, TOK, WTS);
  k_moe_gemm1<<<dim3(32,16,4),256,0,stream>>>(HNB, W1Q, W3Q, CNT, TOK, UP, 0);
  k_moe_gemm2<<<dim3(8,16,4),256,0,stream>>>(UP, W2Q, CNT, TOK, WTS, MA, MB, 0);
  k_moe_gemm1<<<dim3(32,16,4),256,0,stream>>>(HNB, W1Q, W3Q, CNT, TOK, UP, 4);
  k_moe_gemm2<<<dim3(8,16,4),256,0,stream>>>(UP, W2Q, CNT, TOK, WTS, MA, MB, 4);
  k_final<<<2048,256,0,stream>>>(Hb, MA, MB, out);
}